// Round 6
// baseline (222.161 us; speedup 1.0000x reference)
//
#include <hip/hip_runtime.h>
#include <hip/hip_bf16.h>

// Problem constants
#define BT 2048   // batch
#define DD 512    // input dim
#define HH 512    // hidden dim
#define EE 32     // experts
#define KK 4      // top-k
#define CHN 32    // confidence hidden
#define MAXCH 160 // max 64-row chunks: 8192/64 + 32

typedef unsigned int u32;
typedef unsigned short u16;
typedef __attribute__((ext_vector_type(8))) short short8;
typedef __attribute__((ext_vector_type(4))) float f32x4;
typedef __attribute__((ext_vector_type(2))) u32 u32x2;
typedef __attribute__((ext_vector_type(4))) u32 u32x4;

__device__ inline u16 f2bf(float f) {  // RNE float->bf16
  u32 u = __builtin_bit_cast(u32, f);
  u32 r = (u + 0x7FFFu + ((u >> 16) & 1u)) >> 16;
  return (u16)r;
}
__device__ inline u32 pack2bf(float a, float b) {
  return (u32)f2bf(a) | ((u32)f2bf(b) << 16);
}
__device__ inline void gload_lds16(const u32* g, u32* l) {
  __builtin_amdgcn_global_load_lds((const __attribute__((address_space(1))) u32*)g,
                                   (__attribute__((address_space(3))) u32*)l, 16, 0, 0);
}

// ---------------------------------------------------------------------------
// x fp32 -> bf16 row-major.
// ---------------------------------------------------------------------------
__global__ __launch_bounds__(256)
void k_cvt_x(const float* __restrict__ x, u16* __restrict__ xb) {
  int gid = blockIdx.x * 256 + threadIdx.x;
  const float4* src = reinterpret_cast<const float4*>(x) + (size_t)gid * 2;
  float4 a = src[0], b = src[1];
  u32x4 o = { pack2bf(a.x, a.y), pack2bf(a.z, a.w),
              pack2bf(b.x, b.y), pack2bf(b.z, b.w) };
  reinterpret_cast<u32x4*>(xb)[gid] = o;
}

// ---------------------------------------------------------------------------
// W1/W2 -> k-major bf16 fraglet images (transposed weights).
// Image tile (z, nc, s): 8 KB, fraglet(q, col) at u32 [q*512 + col*4] holds
// bf16 W[z][s*32 + q*8 + j][nc*128 + col], j=0..7.  Conflict-free ds_reads.
// grid (2, 16, 64), 256 thr.
// ---------------------------------------------------------------------------
__global__ __launch_bounds__(256)
void k_tr_w(const float* __restrict__ W1, const float* __restrict__ W2,
            u32* __restrict__ img) {
  int n = blockIdx.x * 256 + threadIdx.x;   // 0..511 output col
  int s = blockIdx.y;                        // 0..15 k-step
  int z = blockIdx.z;                        // 0..63 (W1: 0-31, W2: 32-63)
  const float* W = (z < EE) ? (W1 + (size_t)z * DD * HH)
                            : (W2 + (size_t)(z - EE) * HH * DD);
  float v[32];
#pragma unroll
  for (int k = 0; k < 32; k++)
    v[k] = W[(size_t)(s * 32 + k) * 512 + n];
  int nc = n >> 7, coll = n & 127;
  u32* ob = img + ((size_t)(z * 4 + nc) * 16 + s) * 2048 + coll * 4;
#pragma unroll
  for (int g = 0; g < 4; g++) {
    u32x4 fr = { pack2bf(v[g * 8 + 0], v[g * 8 + 1]),
                 pack2bf(v[g * 8 + 2], v[g * 8 + 3]),
                 pack2bf(v[g * 8 + 4], v[g * 8 + 5]),
                 pack2bf(v[g * 8 + 6], v[g * 8 + 7]) };
    *reinterpret_cast<u32x4*>(ob + g * 512) = fr;
  }
}

// ---------------------------------------------------------------------------
// Gating hidden: h = relu(x @ Wg1 + bg1). fp32 (top-k precision).
// grid (B/16, 8) = 1024 blocks (4/CU); tile 16 rows x 64 cols; 4 out/thread.
// ---------------------------------------------------------------------------
__global__ __launch_bounds__(256)
void k_gate_hidden(const float* __restrict__ x, const float* __restrict__ Wg1,
                   const float* __restrict__ bg1, float* __restrict__ h) {
  __shared__ float xs[16][DD];    // 32 KB
  const int tid = threadIdx.x;
  const int row0 = blockIdx.x * 16;
  const int cb = blockIdx.y * 64;
  for (int idx = tid; idx < 16 * 128; idx += 256) {
    int m = idx >> 7, j = idx & 127;
    *reinterpret_cast<float4*>(&xs[m][4 * j]) =
        *reinterpret_cast<const float4*>(&x[(size_t)(row0 + m) * DD + 4 * j]);
  }
  __syncthreads();
  const int cg = tid & 15, rg = tid >> 4;   // 16 rows x 16 col-groups
  const int n0 = cb + cg * 4;
  float4 a0 = {0.f, 0.f, 0.f, 0.f};
  for (int k0 = 0; k0 < DD; k0 += 8) {
    float4 wv[8];
#pragma unroll
    for (int u = 0; u < 8; ++u)
      wv[u] = *reinterpret_cast<const float4*>(&Wg1[(size_t)(k0 + u) * HH + n0]);
    float4 x0 = *reinterpret_cast<const float4*>(&xs[rg][k0]);
    float4 x1 = *reinterpret_cast<const float4*>(&xs[rg][k0 + 4]);
    float xv[8] = {x0.x, x0.y, x0.z, x0.w, x1.x, x1.y, x1.z, x1.w};
#pragma unroll
    for (int u = 0; u < 8; ++u) {
      a0.x = fmaf(xv[u], wv[u].x, a0.x);
      a0.y = fmaf(xv[u], wv[u].y, a0.y);
      a0.z = fmaf(xv[u], wv[u].z, a0.z);
      a0.w = fmaf(xv[u], wv[u].w, a0.w);
    }
  }
  float4 bb = *reinterpret_cast<const float4*>(&bg1[n0]);
  float4 o0;
  o0.x = fmaxf(a0.x + bb.x, 0.f); o0.y = fmaxf(a0.y + bb.y, 0.f);
  o0.z = fmaxf(a0.z + bb.z, 0.f); o0.w = fmaxf(a0.w + bb.w, 0.f);
  *reinterpret_cast<float4*>(&h[(size_t)(row0 + rg) * HH + n0]) = o0;
}

// ---------------------------------------------------------------------------
// Gating logits + softmax + top-4 + routing. 8 tokens/block, 256 thr.
// Wg2 staged fully in LDS (fp32, 64 KB): inner loop is conflict-free
// ds_read_b32 (bank = lane id) + broadcast hb reads. No global latency.
// ---------------------------------------------------------------------------
__global__ __launch_bounds__(256)
void k_gate_route(const float* __restrict__ h, const float* __restrict__ Wg2,
                  const float* __restrict__ bg2, float* __restrict__ wts,
                  int* __restrict__ cnt, int* __restrict__ tlist) {
  __shared__ float wg2s[HH * EE];  // 64 KB, k-major [512][32]
  __shared__ float hb[8][HH];      // 16 KB
  const int tid = threadIdx.x;
  const int t0 = blockIdx.x * 8;
#pragma unroll
  for (int i = 0; i < 16; ++i) {
    int idx = tid + i * 256;       // float4 index, 4096 total
    reinterpret_cast<float4*>(wg2s)[idx] =
        reinterpret_cast<const float4*>(Wg2)[idx];
  }
  for (int idx = tid; idx < 8 * 128; idx += 256) {
    int m = idx >> 7, j = idx & 127;
    *reinterpret_cast<float4*>(&hb[m][4 * j]) =
        *reinterpret_cast<const float4*>(&h[(size_t)(t0 + m) * HH + 4 * j]);
  }
  __syncthreads();
  const int lane = tid & 63, wv = tid >> 6;
  const int e = lane & 31, th = lane >> 5;
  const int lt = wv * 2 + th;          // local token 0..7
  const int t = t0 + lt;
  float ac[4] = {0.f, 0.f, 0.f, 0.f};
  for (int k0 = 0; k0 < HH; k0 += 8) {
    float4 h0 = *reinterpret_cast<const float4*>(&hb[lt][k0]);
    float4 h1 = *reinterpret_cast<const float4*>(&hb[lt][k0 + 4]);
    float hv[8] = {h0.x, h0.y, h0.z, h0.w, h1.x, h1.y, h1.z, h1.w};
#pragma unroll
    for (int u = 0; u < 8; ++u)
      ac[u & 3] = fmaf(hv[u], wg2s[(k0 + u) * EE + e], ac[u & 3]);
  }
  float logit = ((ac[0] + ac[1]) + (ac[2] + ac[3])) + bg2[e];
  // softmax over the 32-lane group
  float mx = logit;
#pragma unroll
  for (int m = 16; m >= 1; m >>= 1) mx = fmaxf(mx, __shfl_xor(mx, m, 32));
  float ex = expf(logit - mx);
  float sm = ex;
#pragma unroll
  for (int m = 16; m >= 1; m >>= 1) sm += __shfl_xor(sm, m, 32);
  float w = ex / sm;
  wts[(size_t)t * EE + e] = w;
  float wcur = w;
  for (int j = 0; j < KK; j++) {
    float v = wcur;
    int vi = e;
#pragma unroll
    for (int m = 16; m >= 1; m >>= 1) {
      float ov = __shfl_xor(v, m, 32);
      int oi = __shfl_xor(vi, m, 32);
      if (ov > v || (ov == v && oi < vi)) { v = ov; vi = oi; }
    }
    if (e == 0) {
      int pos = atomicAdd(&cnt[vi], 1);
      tlist[(size_t)vi * BT + pos] = (t << 2) | j;
    }
    if (e == vi) wcur = -1.f;
  }
}

// ---------------------------------------------------------------------------
// Build chunk tables: chunk c -> (expert, local chunk index). 64 rows/chunk.
// ---------------------------------------------------------------------------
__global__ void k_scan(const int* __restrict__ cnt, int* __restrict__ chunk2e,
                       int* __restrict__ chunkloc) {
  int e = threadIdx.x;
  if (e >= EE) return;
  int off = 0, tot = 0;
  for (int j = 0; j < EE; ++j) {
    int nj = (cnt[j] + 63) >> 6;
    if (j < e) off += nj;
    tot += nj;
  }
  int myn = (cnt[e] + 63) >> 6;
  for (int j = 0; j < myn; ++j) {
    chunk2e[off + j] = e; chunkloc[off + j] = j;
  }
  for (int idx = tot + e; idx < MAXCH; idx += EE) {
    chunk2e[idx] = -1; chunkloc[idx] = 0;
  }
}

// ---------------------------------------------------------------------------
// GEMM1 (grouped, swapped): hidT = W1T(512h x 512k) . xT(512k x 64t).
// Block = (chunk c, h-chunk hc): 128h x 64t tile, BK=64, 4 waves (2x2).
// ---------------------------------------------------------------------------
__global__ __launch_bounds__(256)
void k_gemm1(const u16* __restrict__ xb, const u32* __restrict__ img,
             const float* __restrict__ b1, const int* __restrict__ cnt,
             const int* __restrict__ tlist, const int* __restrict__ chunk2e,
             const int* __restrict__ chunkloc, u32* __restrict__ hid) {
  __shared__ u32 stg[2][4096];   // 2 x 16 KB
  __shared__ int tkl[64];
  const int c = blockIdx.x;
  const int e = chunk2e[c];
  if (e < 0) return;
  const int hc = blockIdx.y;
  const int loc = chunkloc[c];
  const int nt = cnt[e];
  const int tid = threadIdx.x;
  const int w = tid >> 6, lane = tid & 63;
  const int l15 = lane & 15, q = lane >> 4;
  const int wm = w & 1, wn = w >> 1;

  const u32* imgb = img + ((size_t)(e * 4 + hc) * 16) * 2048;
  auto stage = [&](int st, u32* dst) {
    const u32* src = imgb + st * 4096;
#pragma unroll
    for (int i = 0; i < 4; i++)
      gload_lds16(src + tid * 4 + i * 1024, dst + tid * 4 + i * 1024);
  };

  stage(0, stg[0]);
  if (tid < 64) {
    int i = min(loc * 64 + tid, nt - 1);
    tkl[tid] = tlist[(size_t)e * BT + i] >> 2;
  }
  __syncthreads();   // tkl visible + stage(0) drained

  const int t0 = tkl[wn * 32 + l15];
  const int t1 = tkl[wn * 32 + 16 + l15];
  auto ldb = [&](int t, int st, int ss) {
    return *reinterpret_cast<const short8*>(
        xb + (size_t)t * 512 + st * 64 + ss * 32 + q * 8);
  };

  f32x4 acc[4][2];
#pragma unroll
  for (int a = 0; a < 4; a++)
#pragma unroll
    for (int b = 0; b < 2; b++) acc[a][b] = {0.f, 0.f, 0.f, 0.f};

  short8 bfr[2][2];  // [nf][ss]
  bfr[0][0] = ldb(t0, 0, 0); bfr[0][1] = ldb(t0, 0, 1);
  bfr[1][0] = ldb(t1, 0, 0); bfr[1][1] = ldb(t1, 0, 1);

  for (int st = 0; st < 8; ++st) {
    const u32* cur = stg[st & 1];
    short8 nb[2][2];
    if (st < 7) {
      stage(st + 1, stg[(st + 1) & 1]);
      nb[0][0] = ldb(t0, st + 1, 0); nb[0][1] = ldb(t0, st + 1, 1);
      nb[1][0] = ldb(t1, st + 1, 0); nb[1][1] = ldb(t1, st + 1, 1);
    }
#pragma unroll
    for (int ss = 0; ss < 2; ++ss) {
#pragma unroll
      for (int mf = 0; mf < 4; ++mf) {
        int col = wm * 64 + mf * 16 + l15;
        short8 af = *reinterpret_cast<const short8*>(
            cur + ss * 2048 + q * 512 + col * 4);
        acc[mf][0] = __builtin_amdgcn_mfma_f32_16x16x32_bf16(af, bfr[0][ss], acc[mf][0], 0, 0, 0);
        acc[mf][1] = __builtin_amdgcn_mfma_f32_16x16x32_bf16(af, bfr[1][ss], acc[mf][1], 0, 0, 0);
      }
    }
    __syncthreads();   // next stage drained; buffers safe to swap
    if (st < 7) {
      bfr[0][0] = nb[0][0]; bfr[0][1] = nb[0][1];
      bfr[1][0] = nb[1][0]; bfr[1][1] = nb[1][1];
    }
  }

  // epilogue: bias + relu + pack bf16 -> hid[prow][h]
  const float* b1e = b1 + (size_t)e * HH;
#pragma unroll
  for (int mf = 0; mf < 4; ++mf) {
    int h0 = hc * 128 + wm * 64 + mf * 16 + q * 4;
    float4 bb = *reinterpret_cast<const float4*>(b1e + h0);
#pragma unroll
    for (int nf = 0; nf < 2; ++nf) {
      int local = wn * 32 + nf * 16 + l15;
      int prow = c * 64 + local;
      float v0 = fmaxf(acc[mf][nf].x + bb.x, 0.f);
      float v1 = fmaxf(acc[mf][nf].y + bb.y, 0.f);
      float v2 = fmaxf(acc[mf][nf].z + bb.z, 0.f);
      float v3 = fmaxf(acc[mf][nf].w + bb.w, 0.f);
      u32x2 pk = { pack2bf(v0, v1), pack2bf(v2, v3) };
      *reinterpret_cast<u32x2*>(hid + (size_t)prow * 256 + (h0 >> 1)) = pk;
    }
  }
}

// ---------------------------------------------------------------------------
// GEMM2 (grouped, swapped): oT = W2T(512d x 512h) . hidT(512h x 64t).
// ---------------------------------------------------------------------------
__global__ __launch_bounds__(256)
void k_gemm2(const u32* __restrict__ hid, const u32* __restrict__ img,
             const float* __restrict__ b2, const int* __restrict__ cnt,
             const int* __restrict__ tlist, const int* __restrict__ chunk2e,
             const int* __restrict__ chunkloc, float* __restrict__ o_p) {
  __shared__ u32 stg[2][4096];
  __shared__ int tke[64];
  const int c = blockIdx.x;
  const int e = chunk2e[c];
  if (e < 0) return;
  const int dc = blockIdx.y;
  const int loc = chunkloc[c];
  const int nt = cnt[e];
  const int tid = threadIdx.x;
  const int w = tid >> 6, lane = tid & 63;
  const int l15 = lane & 15, q = lane >> 4;
  const int wm = w & 1, wn = w >> 1;
  const int rows_c = min(64, nt - loc * 64);

  const u32* imgb = img + ((size_t)((EE + e) * 4 + dc) * 16) * 2048;
  auto stage = [&](int st, u32* dst) {
    const u32* src = imgb + st * 4096;
#pragma unroll
    for (int i = 0; i < 4; i++)
      gload_lds16(src + tid * 4 + i * 1024, dst + tid * 4 + i * 1024);
  };

  stage(0, stg[0]);
  if (tid < 64) {
    int i = min(loc * 64 + tid, nt - 1);
    tke[tid] = tlist[(size_t)e * BT + i];
  }
  __syncthreads();

  const u16* hid16 = (const u16*)hid;
  const int pr0 = c * 64 + wn * 32 + l15;
  const int pr1 = pr0 + 16;
  auto ldb = [&](int pr, int st, int ss) {
    return *reinterpret_cast<const short8*>(
        hid16 + (size_t)pr * 512 + st * 64 + ss * 32 + q * 8);
  };

  f32x4 acc[4][2];
#pragma unroll
  for (int a = 0; a < 4; a++)
#pragma unroll
    for (int b = 0; b < 2; b++) acc[a][b] = {0.f, 0.f, 0.f, 0.f};

  short8 bfr[2][2];
  bfr[0][0] = ldb(pr0, 0, 0); bfr[0][1] = ldb(pr0, 0, 1);
  bfr[1][0] = ldb(pr1, 0, 0); bfr[1][1] = ldb(pr1, 0, 1);

  for (int st = 0; st < 8; ++st) {
    const u32* cur = stg[st & 1];
    short8 nb[2][2];
    if (st < 7) {
      stage(st + 1, stg[(st + 1) & 1]);
      nb[0][0] = ldb(pr0, st + 1, 0); nb[0][1] = ldb(pr0, st + 1, 1);
      nb[1][0] = ldb(pr1, st + 1, 0); nb[1][1] = ldb(pr1, st + 1, 1);
    }
#pragma unroll
    for (int ss = 0; ss < 2; ++ss) {
#pragma unroll
      for (int mf = 0; mf < 4; ++mf) {
        int col = wm * 64 + mf * 16 + l15;
        short8 af = *reinterpret_cast<const short8*>(
            cur + ss * 2048 + q * 512 + col * 4);
        acc[mf][0] = __builtin_amdgcn_mfma_f32_16x16x32_bf16(af, bfr[0][ss], acc[mf][0], 0, 0, 0);
        acc[mf][1] = __builtin_amdgcn_mfma_f32_16x16x32_bf16(af, bfr[1][ss], acc[mf][1], 0, 0, 0);
      }
    }
    __syncthreads();
    if (st < 7) {
      bfr[0][0] = nb[0][0]; bfr[0][1] = nb[0][1];
      bfr[1][0] = nb[1][0]; bfr[1][1] = nb[1][1];
    }
  }

  // epilogue: bias + scatter fp32 to o_p[(t*K+slot)*D + d] (skip pad rows)
  const float* b2e = b2 + (size_t)e * DD;
#pragma unroll
  for (int mf = 0; mf < 4; ++mf) {
    int d0 = dc * 128 + wm * 64 + mf * 16 + q * 4;
    float4 bb = *reinterpret_cast<const float4*>(b2e + d0);
#pragma unroll
    for (int nf = 0; nf < 2; ++nf) {
      int local = wn * 32 + nf * 16 + l15;
      if (local < rows_c) {
        int ent = tke[local];
        int t = ent >> 2, sl = ent & 3;
        float4 v;
        v.x = acc[mf][nf].x + bb.x;
        v.y = acc[mf][nf].y + bb.y;
        v.z = acc[mf][nf].z + bb.z;
        v.w = acc[mf][nf].w + bb.w;
        *reinterpret_cast<float4*>(&o_p[((size_t)t * KK + sl) * DD + d0]) = v;
      }
    }
  }
}

// ---------------------------------------------------------------------------
// Confidence nets, grouped by expert, LDS-tiled Wc1. grid (BT/16, E), 256 thr.
// ---------------------------------------------------------------------------
__global__ __launch_bounds__(256)
void k_conf(const float* __restrict__ o_p,
            const float* __restrict__ Wc1, const float* __restrict__ bc1,
            const float* __restrict__ Wc2, const float* __restrict__ bc2,
            const float* __restrict__ wts, const int* __restrict__ cnt,
            const int* __restrict__ tlist, float* __restrict__ cw) {
  __shared__ float os[16][DD];     // 32 KB
  __shared__ float wc[128][CHN];   // 16 KB
  __shared__ float chb[16][CHN];
  __shared__ int tkk[16], sll[16];
  const int e = blockIdx.y;
  const int nt = cnt[e];
  const int start = blockIdx.x * 16;
  if (start >= nt) return;
  const int rows = min(16, nt - start);
  const int tid = threadIdx.x;
  if (tid < 16) {
    int i = min(tid, rows - 1);
    int ent = tlist[(size_t)e * BT + start + i];
    tkk[tid] = ent >> 2;
    sll[tid] = ent & 3;
  }
  __syncthreads();
  for (int idx = tid; idx < 16 * 128; idx += 256) {
    int m = idx >> 7, j = idx & 127;
    *reinterpret_cast<float4*>(&os[m][4 * j]) =
        *reinterpret_cast<const float4*>(
            &o_p[((size_t)tkk[m] * KK + sll[m]) * DD + 4 * j]);
  }
  const int cm = tid >> 5;         // 0..7
  const int cc = tid & 31;
  const float* Wc1e = Wc1 + (size_t)e * DD * CHN;
  float a0 = bc1[(size_t)e * CHN + cc];
  float a1 = a0;
  __syncthreads();
  for (int kt = 0; kt < 4; ++kt) {
    // stage Wc1 k-tile (128 x 32 fp32)
#pragma unroll
    for (int i = 0; i < 4; ++i) {
      int fi = tid + i * 256;          // 0..1023 float4s
      int row = fi >> 3, c4 = fi & 7;
      *reinterpret_cast<float4*>(&wc[row][c4 * 4]) =
          *reinterpret_cast<const float4*>(
              &Wc1e[(size_t)(kt * 128 + row) * CHN + c4 * 4]);
    }
    __syncthreads();
#pragma unroll 4
    for (int k = 0; k < 128; ++k) {
      float wv = wc[k][cc];
      a0 = fmaf(os[cm][kt * 128 + k], wv, a0);
      a1 = fmaf(os[cm + 8][kt * 128 + k], wv, a1);
    }
    __syncthreads();
  }
  chb[cm][cc] = fmaxf(a0, 0.f);
  chb[cm + 8][cc] = fmaxf(a1, 0.f);
  __syncthreads();
  if (tid < 16) {
    int m = tid;
    float a = bc2[e];
#pragma unroll
    for (int c = 0; c < CHN; c++)
      a = fmaf(chb[m][c], Wc2[(size_t)e * CHN + c], a);
    float cv = 1.f / (1.f + expf(-a));
    if (m < rows)
      cw[(size_t)tkk[m] * KK + sll[m]] = wts[(size_t)tkk[m] * EE + e] * cv;
  }
}

// ---------------------------------------------------------------------------
// Combine: out[t] = sum_s cw*o / (sum_s cw + eps)
// ---------------------------------------------------------------------------
__global__ __launch_bounds__(256)
void k_combine(const float* __restrict__ o_p, const float* __restrict__ cw,
               float* __restrict__ out) {
  int gid = blockIdx.x * 256 + threadIdx.x;
  int t = gid >> 7;
  int j = gid & 127;
  float c0 = cw[t * 4 + 0], c1 = cw[t * 4 + 1];
  float c2 = cw[t * 4 + 2], c3 = cw[t * 4 + 3];
  float den = c0 + c1 + c2 + c3 + 1e-6f;
  const float4* base = reinterpret_cast<const float4*>(o_p) + (size_t)t * 4 * 128;
  float4 v0 = base[0 * 128 + j];
  float4 v1 = base[1 * 128 + j];
  float4 v2 = base[2 * 128 + j];
  float4 v3 = base[3 * 128 + j];
  float4 r;
  r.x = (c0 * v0.x + c1 * v1.x + c2 * v2.x + c3 * v3.x) / den;
  r.y = (c0 * v0.y + c1 * v1.y + c2 * v2.y + c3 * v3.y) / den;
  r.z = (c0 * v0.z + c1 * v1.z + c2 * v2.z + c3 * v3.z) / den;
  r.w = (c0 * v0.w + c1 * v1.w + c2 * v2.w + c3 * v3.w) / den;
  reinterpret_cast<float4*>(out)[gid] = r;
}

extern "C" void kernel_launch(void* const* d_in, const int* in_sizes, int n_in,
                              void* d_out, int out_size, void* d_ws, size_t ws_size,
                              hipStream_t stream) {
  const float* x   = (const float*)d_in[0];
  const float* W1  = (const float*)d_in[1];
  const float* b1  = (const float*)d_in[2];
  const float* W2  = (const float*)d_in[3];
  const float* b2  = (const float*)d_in[4];
  const float* Wg1 = (const float*)d_in[5];
  const float* bg1 = (const float*)d_in[6];
  const float* Wg2 = (const float*)d_in[7];
  const float* bg2 = (const float*)d_in[8];
  const float* Wc1 = (const float*)d_in[9];
  const float* bc1 = (const float*)d_in[10];
  const float* Wc2 = (const float*)d_in[11];
  const float* bc2 = (const float*)d_in[12];
  float* out = (float*)d_out;

  // workspace layout (~63 MB)
  char* p = (char*)d_ws;
  u16* xb = (u16*)p;            p += (size_t)BT * DD * 2;            // 2 MB
  u32* img = (u32*)p;           p += (size_t)64 * 4 * 16 * 2048 * 4; // 32 MB
  float* h_g = (float*)p;                                            // gate h (4 MB)
  u32* hid = (u32*)p;           p += (size_t)MAXCH * 64 * DD * 2;    // 10 MB (aliases h_g; disjoint in time)
  float* wts = (float*)p;       p += (size_t)BT * EE * 4;            // 256 KB
  float* cw  = (float*)p;       p += (size_t)BT * KK * 4;            // 32 KB
  float* o_p = (float*)p;       p += (size_t)BT * KK * DD * 4;       // 16 MB
  int* cnt = (int*)p;           p += 256;
  int* tlist = (int*)p;         p += (size_t)EE * BT * 4;            // 256 KB
  int* chunk2e = (int*)p;       p += 1024;
  int* chunkloc = (int*)p;      p += 1024;

  hipMemsetAsync(cnt, 0, EE * sizeof(int), stream);
  k_cvt_x<<<(BT * DD) / (256 * 8), 256, 0, stream>>>(x, xb);
  k_tr_w<<<dim3(2, 16, 64), 256, 0, stream>>>(W1, W2, img);
  k_gate_hidden<<<dim3(BT / 16, 8), 256, 0, stream>>>(x, Wg1, bg1, h_g);
  k_gate_route<<<BT / 8, 256, 0, stream>>>(h_g, Wg2, bg2, wts, cnt, tlist);
  k_scan<<<1, 32, 0, stream>>>(cnt, chunk2e, chunkloc);
  k_gemm1<<<dim3(MAXCH, 4), 256, 0, stream>>>(xb, img, b1, cnt, tlist,
                                              chunk2e, chunkloc, hid);
  k_gemm2<<<dim3(MAXCH, 4), 256, 0, stream>>>(hid, img, b2, cnt, tlist,
                                              chunk2e, chunkloc, o_p);
  k_conf<<<dim3(BT / 16, EE), 256, 0, stream>>>(o_p, Wc1, bc1, Wc2, bc2,
                                                wts, cnt, tlist, cw);
  k_combine<<<(BT * (DD / 4)) / 256, 256, 0, stream>>>(o_p, cw, out);
}

// Round 7
// 218.947 us; speedup vs baseline: 1.0147x; 1.0147x over previous
//
#include <hip/hip_runtime.h>
#include <hip/hip_bf16.h>

// Problem constants
#define BT 2048   // batch
#define DD 512    // input dim
#define HH 512    // hidden dim
#define EE 32     // experts
#define KK 4      // top-k
#define CHN 32    // confidence hidden
#define MAXCH 160 // max 64-row chunks: 8192/64 + 32

typedef unsigned int u32;
typedef unsigned short u16;
typedef __attribute__((ext_vector_type(8))) short short8;
typedef __attribute__((ext_vector_type(4))) float f32x4;
typedef __attribute__((ext_vector_type(2))) u32 u32x2;
typedef __attribute__((ext_vector_type(4))) u32 u32x4;

__device__ inline u16 f2bf(float f) {  // RNE float->bf16
  u32 u = __builtin_bit_cast(u32, f);
  u32 r = (u + 0x7FFFu + ((u >> 16) & 1u)) >> 16;
  return (u16)r;
}
__device__ inline u32 pack2bf(float a, float b) {
  return (u32)f2bf(a) | ((u32)f2bf(b) << 16);
}
__device__ inline void gload_lds16(const u32* g, u32* l) {
  __builtin_amdgcn_global_load_lds((const __attribute__((address_space(1))) u32*)g,
                                   (__attribute__((address_space(3))) u32*)l, 16, 0, 0);
}

// ---------------------------------------------------------------------------
// x fp32 -> bf16 row-major.
// ---------------------------------------------------------------------------
__global__ __launch_bounds__(256)
void k_cvt_x(const float* __restrict__ x, u16* __restrict__ xb) {
  int gid = blockIdx.x * 256 + threadIdx.x;
  const float4* src = reinterpret_cast<const float4*>(x) + (size_t)gid * 2;
  float4 a = src[0], b = src[1];
  u32x4 o = { pack2bf(a.x, a.y), pack2bf(a.z, a.w),
              pack2bf(b.x, b.y), pack2bf(b.z, b.w) };
  reinterpret_cast<u32x4*>(xb)[gid] = o;
}

// ---------------------------------------------------------------------------
// W1/W2 -> k-major bf16 fraglet images (transposed weights).
// Image tile (z, nc, s): 8 KB, fraglet(q, col) at u32 [q*512 + col*4] holds
// bf16 W[z][s*32 + q*8 + j][nc*128 + col], j=0..7.  Conflict-free ds_reads.
// grid (2, 16, 64), 256 thr.
// ---------------------------------------------------------------------------
__global__ __launch_bounds__(256)
void k_tr_w(const float* __restrict__ W1, const float* __restrict__ W2,
            u32* __restrict__ img) {
  int n = blockIdx.x * 256 + threadIdx.x;   // 0..511 output col
  int s = blockIdx.y;                        // 0..15 k-step
  int z = blockIdx.z;                        // 0..63 (W1: 0-31, W2: 32-63)
  const float* W = (z < EE) ? (W1 + (size_t)z * DD * HH)
                            : (W2 + (size_t)(z - EE) * HH * DD);
  float v[32];
#pragma unroll
  for (int k = 0; k < 32; k++)
    v[k] = W[(size_t)(s * 32 + k) * 512 + n];
  int nc = n >> 7, coll = n & 127;
  u32* ob = img + ((size_t)(z * 4 + nc) * 16 + s) * 2048 + coll * 4;
#pragma unroll
  for (int g = 0; g < 4; g++) {
    u32x4 fr = { pack2bf(v[g * 8 + 0], v[g * 8 + 1]),
                 pack2bf(v[g * 8 + 2], v[g * 8 + 3]),
                 pack2bf(v[g * 8 + 4], v[g * 8 + 5]),
                 pack2bf(v[g * 8 + 6], v[g * 8 + 7]) };
    *reinterpret_cast<u32x4*>(ob + g * 512) = fr;
  }
}

// ---------------------------------------------------------------------------
// Gating hidden: h = relu(x @ Wg1 + bg1). fp32 (top-k precision).
// grid (B/16, 4) = 512 blocks (2/CU); tile 16r x 128c; 8 out/thread (2r x 4c);
// xs padded (+4) to kill 4-way broadcast bank conflicts; launch_bounds(256,4)
// keeps all 8 weight float4 loads in flight (~90 VGPR).
// ---------------------------------------------------------------------------
__global__ __launch_bounds__(256, 4)
void k_gate_hidden(const float* __restrict__ x, const float* __restrict__ Wg1,
                   const float* __restrict__ bg1, float* __restrict__ h) {
  __shared__ float xs[16][DD + 4];
  const int tid = threadIdx.x;
  const int row0 = blockIdx.x * 16;
  const int cb = blockIdx.y * 128;
  for (int idx = tid; idx < 16 * 128; idx += 256) {
    int m = idx >> 7, j = idx & 127;
    *reinterpret_cast<float4*>(&xs[m][4 * j]) =
        *reinterpret_cast<const float4*>(&x[(size_t)(row0 + m) * DD + 4 * j]);
  }
  __syncthreads();
  const int cg = tid & 31, rg = tid >> 5;   // 32 col-groups x 8 row-groups
  const int n0 = cb + cg * 4;
  const int r0 = rg * 2, r1 = r0 + 1;
  float4 a0 = {0.f, 0.f, 0.f, 0.f}, a1 = {0.f, 0.f, 0.f, 0.f};
  for (int k0 = 0; k0 < DD; k0 += 8) {
    float4 wv[8];
#pragma unroll
    for (int u = 0; u < 8; ++u)
      wv[u] = *reinterpret_cast<const float4*>(&Wg1[(size_t)(k0 + u) * HH + n0]);
#pragma unroll
    for (int u = 0; u < 8; ++u) {
      float xa = xs[r0][k0 + u], xb = xs[r1][k0 + u];
      a0.x = fmaf(xa, wv[u].x, a0.x);
      a0.y = fmaf(xa, wv[u].y, a0.y);
      a0.z = fmaf(xa, wv[u].z, a0.z);
      a0.w = fmaf(xa, wv[u].w, a0.w);
      a1.x = fmaf(xb, wv[u].x, a1.x);
      a1.y = fmaf(xb, wv[u].y, a1.y);
      a1.z = fmaf(xb, wv[u].z, a1.z);
      a1.w = fmaf(xb, wv[u].w, a1.w);
    }
  }
  float4 bb = *reinterpret_cast<const float4*>(&bg1[n0]);
  float4 o0, o1;
  o0.x = fmaxf(a0.x + bb.x, 0.f); o0.y = fmaxf(a0.y + bb.y, 0.f);
  o0.z = fmaxf(a0.z + bb.z, 0.f); o0.w = fmaxf(a0.w + bb.w, 0.f);
  o1.x = fmaxf(a1.x + bb.x, 0.f); o1.y = fmaxf(a1.y + bb.y, 0.f);
  o1.z = fmaxf(a1.z + bb.z, 0.f); o1.w = fmaxf(a1.w + bb.w, 0.f);
  *reinterpret_cast<float4*>(&h[(size_t)(row0 + r0) * HH + n0]) = o0;
  *reinterpret_cast<float4*>(&h[(size_t)(row0 + r1) * HH + n0]) = o1;
}

// ---------------------------------------------------------------------------
// Gating logits + softmax + top-4 + routing. 8 tokens/block, 256 thr.
// Wg2 staged fully in LDS (fp32, 64 KB).
// ---------------------------------------------------------------------------
__global__ __launch_bounds__(256)
void k_gate_route(const float* __restrict__ h, const float* __restrict__ Wg2,
                  const float* __restrict__ bg2, float* __restrict__ wts,
                  int* __restrict__ cnt, int* __restrict__ tlist) {
  __shared__ float wg2s[HH * EE];  // 64 KB, k-major [512][32]
  __shared__ float hb[8][HH];      // 16 KB
  const int tid = threadIdx.x;
  const int t0 = blockIdx.x * 8;
#pragma unroll
  for (int i = 0; i < 16; ++i) {
    int idx = tid + i * 256;       // float4 index, 4096 total
    reinterpret_cast<float4*>(wg2s)[idx] =
        reinterpret_cast<const float4*>(Wg2)[idx];
  }
  for (int idx = tid; idx < 8 * 128; idx += 256) {
    int m = idx >> 7, j = idx & 127;
    *reinterpret_cast<float4*>(&hb[m][4 * j]) =
        *reinterpret_cast<const float4*>(&h[(size_t)(t0 + m) * HH + 4 * j]);
  }
  __syncthreads();
  const int lane = tid & 63, wv = tid >> 6;
  const int e = lane & 31, th = lane >> 5;
  const int lt = wv * 2 + th;          // local token 0..7
  const int t = t0 + lt;
  float ac[4] = {0.f, 0.f, 0.f, 0.f};
  for (int k0 = 0; k0 < HH; k0 += 8) {
    float4 h0 = *reinterpret_cast<const float4*>(&hb[lt][k0]);
    float4 h1 = *reinterpret_cast<const float4*>(&hb[lt][k0 + 4]);
    float hv[8] = {h0.x, h0.y, h0.z, h0.w, h1.x, h1.y, h1.z, h1.w};
#pragma unroll
    for (int u = 0; u < 8; ++u)
      ac[u & 3] = fmaf(hv[u], wg2s[(k0 + u) * EE + e], ac[u & 3]);
  }
  float logit = ((ac[0] + ac[1]) + (ac[2] + ac[3])) + bg2[e];
  // softmax over the 32-lane group
  float mx = logit;
#pragma unroll
  for (int m = 16; m >= 1; m >>= 1) mx = fmaxf(mx, __shfl_xor(mx, m, 32));
  float ex = expf(logit - mx);
  float sm = ex;
#pragma unroll
  for (int m = 16; m >= 1; m >>= 1) sm += __shfl_xor(sm, m, 32);
  float w = ex / sm;
  wts[(size_t)t * EE + e] = w;
  float wcur = w;
  for (int j = 0; j < KK; j++) {
    float v = wcur;
    int vi = e;
#pragma unroll
    for (int m = 16; m >= 1; m >>= 1) {
      float ov = __shfl_xor(v, m, 32);
      int oi = __shfl_xor(vi, m, 32);
      if (ov > v || (ov == v && oi < vi)) { v = ov; vi = oi; }
    }
    if (e == 0) {
      int pos = atomicAdd(&cnt[vi], 1);
      tlist[(size_t)vi * BT + pos] = (t << 2) | j;
    }
    if (e == vi) wcur = -1.f;
  }
}

// ---------------------------------------------------------------------------
// Build chunk tables: chunk c -> (expert, local chunk index). 64 rows/chunk.
// ---------------------------------------------------------------------------
__global__ void k_scan(const int* __restrict__ cnt, int* __restrict__ chunk2e,
                       int* __restrict__ chunkloc) {
  int e = threadIdx.x;
  if (e >= EE) return;
  int off = 0, tot = 0;
  for (int j = 0; j < EE; ++j) {
    int nj = (cnt[j] + 63) >> 6;
    if (j < e) off += nj;
    tot += nj;
  }
  int myn = (cnt[e] + 63) >> 6;
  for (int j = 0; j < myn; ++j) {
    chunk2e[off + j] = e; chunkloc[off + j] = j;
  }
  for (int idx = tot + e; idx < MAXCH; idx += EE) {
    chunk2e[idx] = -1; chunkloc[idx] = 0;
  }
}

// XCD-affinity chunk remap: dispatcher round-robins flat block id over 8 XCDs;
// map bx so chunk ids 0..19 land on XCD0, 20..39 on XCD1, ... -> all chunks of
// one expert (consecutive ids) share an XCD and its L2-resident weight image.
__device__ inline int remap_chunk(int bx) {
  return (bx & 7) * (MAXCH / 8) + (bx >> 3);
}

// ---------------------------------------------------------------------------
// GEMM1 (grouped, swapped): hidT = W1T(512h x 512k) . xT(512k x 64t).
// Block = (chunk c, h-chunk hc): 128h x 64t tile, BK=64, 4 waves (2x2).
// ---------------------------------------------------------------------------
__global__ __launch_bounds__(256)
void k_gemm1(const u16* __restrict__ xb, const u32* __restrict__ img,
             const float* __restrict__ b1, const int* __restrict__ cnt,
             const int* __restrict__ tlist, const int* __restrict__ chunk2e,
             const int* __restrict__ chunkloc, u32* __restrict__ hid) {
  __shared__ u32 stg[2][4096];   // 2 x 16 KB
  __shared__ int tkl[64];
  const int c = remap_chunk(blockIdx.x);
  const int e = chunk2e[c];
  if (e < 0) return;
  const int hc = blockIdx.y;
  const int loc = chunkloc[c];
  const int nt = cnt[e];
  const int tid = threadIdx.x;
  const int w = tid >> 6, lane = tid & 63;
  const int l15 = lane & 15, q = lane >> 4;
  const int wm = w & 1, wn = w >> 1;

  const u32* imgb = img + ((size_t)(e * 4 + hc) * 16) * 2048;
  auto stage = [&](int st, u32* dst) {
    const u32* src = imgb + st * 4096;
#pragma unroll
    for (int i = 0; i < 4; i++)
      gload_lds16(src + tid * 4 + i * 1024, dst + tid * 4 + i * 1024);
  };

  stage(0, stg[0]);
  if (tid < 64) {
    int i = min(loc * 64 + tid, nt - 1);
    tkl[tid] = tlist[(size_t)e * BT + i] >> 2;
  }
  __syncthreads();   // tkl visible + stage(0) drained

  const int t0 = tkl[wn * 32 + l15];
  const int t1 = tkl[wn * 32 + 16 + l15];
  auto ldb = [&](int t, int st, int ss) {
    return *reinterpret_cast<const short8*>(
        xb + (size_t)t * 512 + st * 64 + ss * 32 + q * 8);
  };

  f32x4 acc[4][2];
#pragma unroll
  for (int a = 0; a < 4; a++)
#pragma unroll
    for (int b = 0; b < 2; b++) acc[a][b] = {0.f, 0.f, 0.f, 0.f};

  short8 bfr[2][2];  // [nf][ss]
  bfr[0][0] = ldb(t0, 0, 0); bfr[0][1] = ldb(t0, 0, 1);
  bfr[1][0] = ldb(t1, 0, 0); bfr[1][1] = ldb(t1, 0, 1);

  for (int st = 0; st < 8; ++st) {
    const u32* cur = stg[st & 1];
    short8 nb[2][2];
    if (st < 7) {
      stage(st + 1, stg[(st + 1) & 1]);
      nb[0][0] = ldb(t0, st + 1, 0); nb[0][1] = ldb(t0, st + 1, 1);
      nb[1][0] = ldb(t1, st + 1, 0); nb[1][1] = ldb(t1, st + 1, 1);
    }
#pragma unroll
    for (int ss = 0; ss < 2; ++ss) {
#pragma unroll
      for (int mf = 0; mf < 4; ++mf) {
        int col = wm * 64 + mf * 16 + l15;
        short8 af = *reinterpret_cast<const short8*>(
            cur + ss * 2048 + q * 512 + col * 4);
        acc[mf][0] = __builtin_amdgcn_mfma_f32_16x16x32_bf16(af, bfr[0][ss], acc[mf][0], 0, 0, 0);
        acc[mf][1] = __builtin_amdgcn_mfma_f32_16x16x32_bf16(af, bfr[1][ss], acc[mf][1], 0, 0, 0);
      }
    }
    __syncthreads();   // next stage drained; buffers safe to swap
    if (st < 7) {
      bfr[0][0] = nb[0][0]; bfr[0][1] = nb[0][1];
      bfr[1][0] = nb[1][0]; bfr[1][1] = nb[1][1];
    }
  }

  // epilogue: bias + relu + pack bf16 -> hid[prow][h]
  const float* b1e = b1 + (size_t)e * HH;
#pragma unroll
  for (int mf = 0; mf < 4; ++mf) {
    int h0 = hc * 128 + wm * 64 + mf * 16 + q * 4;
    float4 bb = *reinterpret_cast<const float4*>(b1e + h0);
#pragma unroll
    for (int nf = 0; nf < 2; ++nf) {
      int local = wn * 32 + nf * 16 + l15;
      int prow = c * 64 + local;
      float v0 = fmaxf(acc[mf][nf].x + bb.x, 0.f);
      float v1 = fmaxf(acc[mf][nf].y + bb.y, 0.f);
      float v2 = fmaxf(acc[mf][nf].z + bb.z, 0.f);
      float v3 = fmaxf(acc[mf][nf].w + bb.w, 0.f);
      u32x2 pk = { pack2bf(v0, v1), pack2bf(v2, v3) };
      *reinterpret_cast<u32x2*>(hid + (size_t)prow * 256 + (h0 >> 1)) = pk;
    }
  }
}

// ---------------------------------------------------------------------------
// GEMM2 (grouped, swapped): oT = W2T(512d x 512h) . hidT(512h x 64t).
// ---------------------------------------------------------------------------
__global__ __launch_bounds__(256)
void k_gemm2(const u32* __restrict__ hid, const u32* __restrict__ img,
             const float* __restrict__ b2, const int* __restrict__ cnt,
             const int* __restrict__ tlist, const int* __restrict__ chunk2e,
             const int* __restrict__ chunkloc, float* __restrict__ o_p) {
  __shared__ u32 stg[2][4096];
  __shared__ int tke[64];
  const int c = remap_chunk(blockIdx.x);
  const int e = chunk2e[c];
  if (e < 0) return;
  const int dc = blockIdx.y;
  const int loc = chunkloc[c];
  const int nt = cnt[e];
  const int tid = threadIdx.x;
  const int w = tid >> 6, lane = tid & 63;
  const int l15 = lane & 15, q = lane >> 4;
  const int wm = w & 1, wn = w >> 1;
  const int rows_c = min(64, nt - loc * 64);

  const u32* imgb = img + ((size_t)((EE + e) * 4 + dc) * 16) * 2048;
  auto stage = [&](int st, u32* dst) {
    const u32* src = imgb + st * 4096;
#pragma unroll
    for (int i = 0; i < 4; i++)
      gload_lds16(src + tid * 4 + i * 1024, dst + tid * 4 + i * 1024);
  };

  stage(0, stg[0]);
  if (tid < 64) {
    int i = min(loc * 64 + tid, nt - 1);
    tke[tid] = tlist[(size_t)e * BT + i];
  }
  __syncthreads();

  const u16* hid16 = (const u16*)hid;
  const int pr0 = c * 64 + wn * 32 + l15;
  const int pr1 = pr0 + 16;
  auto ldb = [&](int pr, int st, int ss) {
    return *reinterpret_cast<const short8*>(
        hid16 + (size_t)pr * 512 + st * 64 + ss * 32 + q * 8);
  };

  f32x4 acc[4][2];
#pragma unroll
  for (int a = 0; a < 4; a++)
#pragma unroll
    for (int b = 0; b < 2; b++) acc[a][b] = {0.f, 0.f, 0.f, 0.f};

  short8 bfr[2][2];
  bfr[0][0] = ldb(pr0, 0, 0); bfr[0][1] = ldb(pr0, 0, 1);
  bfr[1][0] = ldb(pr1, 0, 0); bfr[1][1] = ldb(pr1, 0, 1);

  for (int st = 0; st < 8; ++st) {
    const u32* cur = stg[st & 1];
    short8 nb[2][2];
    if (st < 7) {
      stage(st + 1, stg[(st + 1) & 1]);
      nb[0][0] = ldb(pr0, st + 1, 0); nb[0][1] = ldb(pr0, st + 1, 1);
      nb[1][0] = ldb(pr1, st + 1, 0); nb[1][1] = ldb(pr1, st + 1, 1);
    }
#pragma unroll
    for (int ss = 0; ss < 2; ++ss) {
#pragma unroll
      for (int mf = 0; mf < 4; ++mf) {
        int col = wm * 64 + mf * 16 + l15;
        short8 af = *reinterpret_cast<const short8*>(
            cur + ss * 2048 + q * 512 + col * 4);
        acc[mf][0] = __builtin_amdgcn_mfma_f32_16x16x32_bf16(af, bfr[0][ss], acc[mf][0], 0, 0, 0);
        acc[mf][1] = __builtin_amdgcn_mfma_f32_16x16x32_bf16(af, bfr[1][ss], acc[mf][1], 0, 0, 0);
      }
    }
    __syncthreads();
    if (st < 7) {
      bfr[0][0] = nb[0][0]; bfr[0][1] = nb[0][1];
      bfr[1][0] = nb[1][0]; bfr[1][1] = nb[1][1];
    }
  }

  // epilogue: bias + scatter fp32 to o_p[(t*K+slot)*D + d] (skip pad rows)
  const float* b2e = b2 + (size_t)e * DD;
#pragma unroll
  for (int mf = 0; mf < 4; ++mf) {
    int d0 = dc * 128 + wm * 64 + mf * 16 + q * 4;
    float4 bb = *reinterpret_cast<const float4*>(b2e + d0);
#pragma unroll
    for (int nf = 0; nf < 2; ++nf) {
      int local = wn * 32 + nf * 16 + l15;
      if (local < rows_c) {
        int ent = tke[local];
        int t = ent >> 2, sl = ent & 3;
        float4 v;
        v.x = acc[mf][nf].x + bb.x;
        v.y = acc[mf][nf].y + bb.y;
        v.z = acc[mf][nf].z + bb.z;
        v.w = acc[mf][nf].w + bb.w;
        *reinterpret_cast<float4*>(&o_p[((size_t)t * KK + sl) * DD + d0]) = v;
      }
    }
  }
}

// ---------------------------------------------------------------------------
// Confidence nets, grouped by expert, LDS-tiled Wc1. grid (EE, BT/16):
// expert = blockIdx.x so same-expert blocks share an XCD (Wc1 L2-resident).
// ---------------------------------------------------------------------------
__global__ __launch_bounds__(256)
void k_conf(const float* __restrict__ o_p,
            const float* __restrict__ Wc1, const float* __restrict__ bc1,
            const float* __restrict__ Wc2, const float* __restrict__ bc2,
            const float* __restrict__ wts, const int* __restrict__ cnt,
            const int* __restrict__ tlist, float* __restrict__ cw) {
  __shared__ float os[16][DD];     // 32 KB
  __shared__ float wc[128][CHN];   // 16 KB
  __shared__ float chb[16][CHN];
  __shared__ int tkk[16], sll[16];
  const int e = blockIdx.x;
  const int nt = cnt[e];
  const int start = blockIdx.y * 16;
  if (start >= nt) return;
  const int rows = min(16, nt - start);
  const int tid = threadIdx.x;
  if (tid < 16) {
    int i = min(tid, rows - 1);
    int ent = tlist[(size_t)e * BT + start + i];
    tkk[tid] = ent >> 2;
    sll[tid] = ent & 3;
  }
  __syncthreads();
  for (int idx = tid; idx < 16 * 128; idx += 256) {
    int m = idx >> 7, j = idx & 127;
    *reinterpret_cast<float4*>(&os[m][4 * j]) =
        *reinterpret_cast<const float4*>(
            &o_p[((size_t)tkk[m] * KK + sll[m]) * DD + 4 * j]);
  }
  const int cm = tid >> 5;         // 0..7
  const int cc = tid & 31;
  const float* Wc1e = Wc1 + (size_t)e * DD * CHN;
  float a0 = bc1[(size_t)e * CHN + cc];
  float a1 = a0;
  __syncthreads();
  for (int kt = 0; kt < 4; ++kt) {
    // stage Wc1 k-tile (128 x 32 fp32)
#pragma unroll
    for (int i = 0; i < 4; ++i) {
      int fi = tid + i * 256;          // 0..1023 float4s
      int row = fi >> 3, c4 = fi & 7;
      *reinterpret_cast<float4*>(&wc[row][c4 * 4]) =
          *reinterpret_cast<const float4*>(
              &Wc1e[(size_t)(kt * 128 + row) * CHN + c4 * 4]);
    }
    __syncthreads();
#pragma unroll 4
    for (int k = 0; k < 128; ++k) {
      float wv = wc[k][cc];
      a0 = fmaf(os[cm][kt * 128 + k], wv, a0);
      a1 = fmaf(os[cm + 8][kt * 128 + k], wv, a1);
    }
    __syncthreads();
  }
  chb[cm][cc] = fmaxf(a0, 0.f);
  chb[cm + 8][cc] = fmaxf(a1, 0.f);
  __syncthreads();
  if (tid < 16) {
    int m = tid;
    float a = bc2[e];
#pragma unroll
    for (int c = 0; c < CHN; c++)
      a = fmaf(chb[m][c], Wc2[(size_t)e * CHN + c], a);
    float cv = 1.f / (1.f + expf(-a));
    if (m < rows)
      cw[(size_t)tkk[m] * KK + sll[m]] = wts[(size_t)tkk[m] * EE + e] * cv;
  }
}

// ---------------------------------------------------------------------------
// Combine: out[t] = sum_s cw*o / (sum_s cw + eps)
// ---------------------------------------------------------------------------
__global__ __launch_bounds__(256)
void k_combine(const float* __restrict__ o_p, const float* __restrict__ cw,
               float* __restrict__ out) {
  int gid = blockIdx.x * 256 + threadIdx.x;
  int t = gid >> 7;
  int j = gid & 127;
  float c0 = cw[t * 4 + 0], c1 = cw[t * 4 + 1];
  float c2 = cw[t * 4 + 2], c3 = cw[t * 4 + 3];
  float den = c0 + c1 + c2 + c3 + 1e-6f;
  const float4* base = reinterpret_cast<const float4*>(o_p) + (size_t)t * 4 * 128;
  float4 v0 = base[0 * 128 + j];
  float4 v1 = base[1 * 128 + j];
  float4 v2 = base[2 * 128 + j];
  float4 v3 = base[3 * 128 + j];
  float4 r;
  r.x = (c0 * v0.x + c1 * v1.x + c2 * v2.x + c3 * v3.x) / den;
  r.y = (c0 * v0.y + c1 * v1.y + c2 * v2.y + c3 * v3.y) / den;
  r.z = (c0 * v0.z + c1 * v1.z + c2 * v2.z + c3 * v3.z) / den;
  r.w = (c0 * v0.w + c1 * v1.w + c2 * v2.w + c3 * v3.w) / den;
  reinterpret_cast<float4*>(out)[gid] = r;
}

extern "C" void kernel_launch(void* const* d_in, const int* in_sizes, int n_in,
                              void* d_out, int out_size, void* d_ws, size_t ws_size,
                              hipStream_t stream) {
  const float* x   = (const float*)d_in[0];
  const float* W1  = (const float*)d_in[1];
  const float* b1  = (const float*)d_in[2];
  const float* W2  = (const float*)d_in[3];
  const float* b2  = (const float*)d_in[4];
  const float* Wg1 = (const float*)d_in[5];
  const float* bg1 = (const float*)d_in[6];
  const float* Wg2 = (const float*)d_in[7];
  const float* bg2 = (const float*)d_in[8];
  const float* Wc1 = (const float*)d_in[9];
  const float* bc1 = (const float*)d_in[10];
  const float* Wc2 = (const float*)d_in[11];
  const float* bc2 = (const float*)d_in[12];
  float* out = (float*)d_out;

  // workspace layout (~63 MB)
  char* p = (char*)d_ws;
  u16* xb = (u16*)p;            p += (size_t)BT * DD * 2;            // 2 MB
  u32* img = (u32*)p;           p += (size_t)64 * 4 * 16 * 2048 * 4; // 32 MB
  float* h_g = (float*)p;                                            // gate h (4 MB)
  u32* hid = (u32*)p;           p += (size_t)MAXCH * 64 * DD * 2;    // 10 MB (aliases h_g; disjoint in time)
  float* wts = (float*)p;       p += (size_t)BT * EE * 4;            // 256 KB
  float* cw  = (float*)p;       p += (size_t)BT * KK * 4;            // 32 KB
  float* o_p = (float*)p;       p += (size_t)BT * KK * DD * 4;       // 16 MB
  int* cnt = (int*)p;           p += 256;
  int* tlist = (int*)p;         p += (size_t)EE * BT * 4;            // 256 KB
  int* chunk2e = (int*)p;       p += 1024;
  int* chunkloc = (int*)p;      p += 1024;

  hipMemsetAsync(cnt, 0, EE * sizeof(int), stream);
  k_cvt_x<<<(BT * DD) / (256 * 8), 256, 0, stream>>>(x, xb);
  k_tr_w<<<dim3(2, 16, 64), 256, 0, stream>>>(W1, W2, img);
  k_gate_hidden<<<dim3(BT / 16, 4), 256, 0, stream>>>(x, Wg1, bg1, h_g);
  k_gate_route<<<BT / 8, 256, 0, stream>>>(h_g, Wg2, bg2, wts, cnt, tlist);
  k_scan<<<1, 32, 0, stream>>>(cnt, chunk2e, chunkloc);
  k_gemm1<<<dim3(MAXCH, 4), 256, 0, stream>>>(xb, img, b1, cnt, tlist,
                                              chunk2e, chunkloc, hid);
  k_gemm2<<<dim3(MAXCH, 4), 256, 0, stream>>>(hid, img, b2, cnt, tlist,
                                              chunk2e, chunkloc, o_p);
  k_conf<<<dim3(EE, BT / 16), 256, 0, stream>>>(o_p, Wc1, bc1, Wc2, bc2,
                                                wts, cnt, tlist, cw);
  k_combine<<<(BT * (DD / 4)) / 256, 256, 0, stream>>>(o_p, cw, out);
}

// Round 8
// 166.739 us; speedup vs baseline: 1.3324x; 1.3131x over previous
//
#include <hip/hip_runtime.h>
#include <hip/hip_bf16.h>

// Problem constants
#define BT 2048   // batch
#define DD 512    // input dim
#define HH 512    // hidden dim
#define EE 32     // experts
#define KK 4      // top-k
#define CHN 32    // confidence hidden
#define MAXCH 160 // max 64-row chunks: 8192/64 + 32

typedef unsigned int u32;
typedef unsigned short u16;
typedef __attribute__((ext_vector_type(8))) short short8;
typedef __attribute__((ext_vector_type(4))) float f32x4;
typedef __attribute__((ext_vector_type(2))) u32 u32x2;
typedef __attribute__((ext_vector_type(4))) u32 u32x4;

__device__ inline u16 f2bf(float f) {  // RNE float->bf16
  u32 u = __builtin_bit_cast(u32, f);
  u32 r = (u + 0x7FFFu + ((u >> 16) & 1u)) >> 16;
  return (u16)r;
}
__device__ inline u32 pack2bf(float a, float b) {
  return (u32)f2bf(a) | ((u32)f2bf(b) << 16);
}
__device__ inline void gload_lds16(const u32* g, u32* l) {
  __builtin_amdgcn_global_load_lds((const __attribute__((address_space(1))) u32*)g,
                                   (__attribute__((address_space(3))) u32*)l, 16, 0, 0);
}

// ---------------------------------------------------------------------------
// x fp32 -> bf16 row-major.
// ---------------------------------------------------------------------------
__global__ __launch_bounds__(256)
void k_cvt_x(const float* __restrict__ x, u16* __restrict__ xb) {
  int gid = blockIdx.x * 256 + threadIdx.x;
  const float4* src = reinterpret_cast<const float4*>(x) + (size_t)gid * 2;
  float4 a = src[0], b = src[1];
  u32x4 o = { pack2bf(a.x, a.y), pack2bf(a.z, a.w),
              pack2bf(b.x, b.y), pack2bf(b.z, b.w) };
  reinterpret_cast<u32x4*>(xb)[gid] = o;
}

// ---------------------------------------------------------------------------
// W1/W2 -> k-major bf16 fraglet images (transposed weights).
// Image tile (z, nc, s): 8 KB, fraglet(q, col) at u32 [q*512 + col*4] holds
// bf16 W[z][s*32 + q*8 + j][nc*128 + col], j=0..7.  Conflict-free ds_reads.
// grid (2, 16, 64), 256 thr.
// ---------------------------------------------------------------------------
__global__ __launch_bounds__(256)
void k_tr_w(const float* __restrict__ W1, const float* __restrict__ W2,
            u32* __restrict__ img) {
  int n = blockIdx.x * 256 + threadIdx.x;   // 0..511 output col
  int s = blockIdx.y;                        // 0..15 k-step
  int z = blockIdx.z;                        // 0..63 (W1: 0-31, W2: 32-63)
  const float* W = (z < EE) ? (W1 + (size_t)z * DD * HH)
                            : (W2 + (size_t)(z - EE) * HH * DD);
  float v[32];
#pragma unroll
  for (int k = 0; k < 32; k++)
    v[k] = W[(size_t)(s * 32 + k) * 512 + n];
  int nc = n >> 7, coll = n & 127;
  u32* ob = img + ((size_t)(z * 4 + nc) * 16 + s) * 2048 + coll * 4;
#pragma unroll
  for (int g = 0; g < 4; g++) {
    u32x4 fr = { pack2bf(v[g * 8 + 0], v[g * 8 + 1]),
                 pack2bf(v[g * 8 + 2], v[g * 8 + 3]),
                 pack2bf(v[g * 8 + 4], v[g * 8 + 5]),
                 pack2bf(v[g * 8 + 6], v[g * 8 + 7]) };
    *reinterpret_cast<u32x4*>(ob + g * 512) = fr;
  }
}

// ---------------------------------------------------------------------------
// Wc1 -> bf16 k-major fraglet image for conf MFMA.
// Per (e, s): 512 u32 (2 KB); fraglet(q, col) at u32 [q*128 + col*4] holds
// bf16 Wc1[e][s*32 + q*8 + j][col], j=0..7. 32 KB/expert, 1 MB total.
// grid (EE, 16), 128 thr.
// ---------------------------------------------------------------------------
__global__ __launch_bounds__(128)
void k_tr_wc(const float* __restrict__ Wc1, u32* __restrict__ img_c) {
  int e = blockIdx.x, s = blockIdx.y;
  int tid = threadIdx.x;
  int q = tid >> 5, col = tid & 31;
  const float* W = Wc1 + (size_t)e * DD * CHN;
  float v[8];
#pragma unroll
  for (int j = 0; j < 8; ++j)
    v[j] = W[(size_t)(s * 32 + q * 8 + j) * CHN + col];
  u32x4 fr = { pack2bf(v[0], v[1]), pack2bf(v[2], v[3]),
               pack2bf(v[4], v[5]), pack2bf(v[6], v[7]) };
  *reinterpret_cast<u32x4*>(img_c + ((size_t)e * 16 + s) * 512 + q * 128 + col * 4) = fr;
}

// ---------------------------------------------------------------------------
// Gating hidden: h = relu(x @ Wg1 + bg1). fp32 (top-k precision).
// ---------------------------------------------------------------------------
__global__ __launch_bounds__(256, 4)
void k_gate_hidden(const float* __restrict__ x, const float* __restrict__ Wg1,
                   const float* __restrict__ bg1, float* __restrict__ h) {
  __shared__ float xs[16][DD + 4];
  const int tid = threadIdx.x;
  const int row0 = blockIdx.x * 16;
  const int cb = blockIdx.y * 128;
  for (int idx = tid; idx < 16 * 128; idx += 256) {
    int m = idx >> 7, j = idx & 127;
    *reinterpret_cast<float4*>(&xs[m][4 * j]) =
        *reinterpret_cast<const float4*>(&x[(size_t)(row0 + m) * DD + 4 * j]);
  }
  __syncthreads();
  const int cg = tid & 31, rg = tid >> 5;   // 32 col-groups x 8 row-groups
  const int n0 = cb + cg * 4;
  const int r0 = rg * 2, r1 = r0 + 1;
  float4 a0 = {0.f, 0.f, 0.f, 0.f}, a1 = {0.f, 0.f, 0.f, 0.f};
  for (int k0 = 0; k0 < DD; k0 += 8) {
    float4 wv[8];
#pragma unroll
    for (int u = 0; u < 8; ++u)
      wv[u] = *reinterpret_cast<const float4*>(&Wg1[(size_t)(k0 + u) * HH + n0]);
#pragma unroll
    for (int u = 0; u < 8; ++u) {
      float xa = xs[r0][k0 + u], xb = xs[r1][k0 + u];
      a0.x = fmaf(xa, wv[u].x, a0.x);
      a0.y = fmaf(xa, wv[u].y, a0.y);
      a0.z = fmaf(xa, wv[u].z, a0.z);
      a0.w = fmaf(xa, wv[u].w, a0.w);
      a1.x = fmaf(xb, wv[u].x, a1.x);
      a1.y = fmaf(xb, wv[u].y, a1.y);
      a1.z = fmaf(xb, wv[u].z, a1.z);
      a1.w = fmaf(xb, wv[u].w, a1.w);
    }
  }
  float4 bb = *reinterpret_cast<const float4*>(&bg1[n0]);
  float4 o0, o1;
  o0.x = fmaxf(a0.x + bb.x, 0.f); o0.y = fmaxf(a0.y + bb.y, 0.f);
  o0.z = fmaxf(a0.z + bb.z, 0.f); o0.w = fmaxf(a0.w + bb.w, 0.f);
  o1.x = fmaxf(a1.x + bb.x, 0.f); o1.y = fmaxf(a1.y + bb.y, 0.f);
  o1.z = fmaxf(a1.z + bb.z, 0.f); o1.w = fmaxf(a1.w + bb.w, 0.f);
  *reinterpret_cast<float4*>(&h[(size_t)(row0 + r0) * HH + n0]) = o0;
  *reinterpret_cast<float4*>(&h[(size_t)(row0 + r1) * HH + n0]) = o1;
}

// ---------------------------------------------------------------------------
// Gating logits + softmax + top-4 + routing. 8 tokens/block, 256 thr.
// Wg2 staged fully in LDS (fp32, 64 KB).
// ---------------------------------------------------------------------------
__global__ __launch_bounds__(256)
void k_gate_route(const float* __restrict__ h, const float* __restrict__ Wg2,
                  const float* __restrict__ bg2, float* __restrict__ wts,
                  int* __restrict__ cnt, int* __restrict__ tlist) {
  __shared__ float wg2s[HH * EE];  // 64 KB, k-major [512][32]
  __shared__ float hb[8][HH];      // 16 KB
  const int tid = threadIdx.x;
  const int t0 = blockIdx.x * 8;
#pragma unroll
  for (int i = 0; i < 16; ++i) {
    int idx = tid + i * 256;       // float4 index, 4096 total
    reinterpret_cast<float4*>(wg2s)[idx] =
        reinterpret_cast<const float4*>(Wg2)[idx];
  }
  for (int idx = tid; idx < 8 * 128; idx += 256) {
    int m = idx >> 7, j = idx & 127;
    *reinterpret_cast<float4*>(&hb[m][4 * j]) =
        *reinterpret_cast<const float4*>(&h[(size_t)(t0 + m) * HH + 4 * j]);
  }
  __syncthreads();
  const int lane = tid & 63, wv = tid >> 6;
  const int e = lane & 31, th = lane >> 5;
  const int lt = wv * 2 + th;          // local token 0..7
  const int t = t0 + lt;
  float ac[4] = {0.f, 0.f, 0.f, 0.f};
  for (int k0 = 0; k0 < HH; k0 += 8) {
    float4 h0 = *reinterpret_cast<const float4*>(&hb[lt][k0]);
    float4 h1 = *reinterpret_cast<const float4*>(&hb[lt][k0 + 4]);
    float hv[8] = {h0.x, h0.y, h0.z, h0.w, h1.x, h1.y, h1.z, h1.w};
#pragma unroll
    for (int u = 0; u < 8; ++u)
      ac[u & 3] = fmaf(hv[u], wg2s[(k0 + u) * EE + e], ac[u & 3]);
  }
  float logit = ((ac[0] + ac[1]) + (ac[2] + ac[3])) + bg2[e];
  // softmax over the 32-lane group
  float mx = logit;
#pragma unroll
  for (int m = 16; m >= 1; m >>= 1) mx = fmaxf(mx, __shfl_xor(mx, m, 32));
  float ex = expf(logit - mx);
  float sm = ex;
#pragma unroll
  for (int m = 16; m >= 1; m >>= 1) sm += __shfl_xor(sm, m, 32);
  float w = ex / sm;
  wts[(size_t)t * EE + e] = w;
  float wcur = w;
  for (int j = 0; j < KK; j++) {
    float v = wcur;
    int vi = e;
#pragma unroll
    for (int m = 16; m >= 1; m >>= 1) {
      float ov = __shfl_xor(v, m, 32);
      int oi = __shfl_xor(vi, m, 32);
      if (ov > v || (ov == v && oi < vi)) { v = ov; vi = oi; }
    }
    if (e == 0) {
      int pos = atomicAdd(&cnt[vi], 1);
      tlist[(size_t)vi * BT + pos] = (t << 2) | j;
    }
    if (e == vi) wcur = -1.f;
  }
}

// ---------------------------------------------------------------------------
// Build chunk tables: chunk c -> (expert, local chunk index). 64 rows/chunk.
// ---------------------------------------------------------------------------
__global__ void k_scan(const int* __restrict__ cnt, int* __restrict__ chunk2e,
                       int* __restrict__ chunkloc) {
  int e = threadIdx.x;
  if (e >= EE) return;
  int off = 0, tot = 0;
  for (int j = 0; j < EE; ++j) {
    int nj = (cnt[j] + 63) >> 6;
    if (j < e) off += nj;
    tot += nj;
  }
  int myn = (cnt[e] + 63) >> 6;
  for (int j = 0; j < myn; ++j) {
    chunk2e[off + j] = e; chunkloc[off + j] = j;
  }
  for (int idx = tot + e; idx < MAXCH; idx += EE) {
    chunk2e[idx] = -1; chunkloc[idx] = 0;
  }
}

// XCD-affinity chunk remap.
__device__ inline int remap_chunk(int bx) {
  return (bx & 7) * (MAXCH / 8) + (bx >> 3);
}

// ---------------------------------------------------------------------------
// GEMM1 (grouped, swapped): hidT = W1T(512h x 512k) . xT(512k x 64t).
// ---------------------------------------------------------------------------
__global__ __launch_bounds__(256)
void k_gemm1(const u16* __restrict__ xb, const u32* __restrict__ img,
             const float* __restrict__ b1, const int* __restrict__ cnt,
             const int* __restrict__ tlist, const int* __restrict__ chunk2e,
             const int* __restrict__ chunkloc, u32* __restrict__ hid) {
  __shared__ u32 stg[2][4096];   // 2 x 16 KB
  __shared__ int tkl[64];
  const int c = remap_chunk(blockIdx.x);
  const int e = chunk2e[c];
  if (e < 0) return;
  const int hc = blockIdx.y;
  const int loc = chunkloc[c];
  const int nt = cnt[e];
  const int tid = threadIdx.x;
  const int w = tid >> 6, lane = tid & 63;
  const int l15 = lane & 15, q = lane >> 4;
  const int wm = w & 1, wn = w >> 1;

  const u32* imgb = img + ((size_t)(e * 4 + hc) * 16) * 2048;
  auto stage = [&](int st, u32* dst) {
    const u32* src = imgb + st * 4096;
#pragma unroll
    for (int i = 0; i < 4; i++)
      gload_lds16(src + tid * 4 + i * 1024, dst + tid * 4 + i * 1024);
  };

  stage(0, stg[0]);
  if (tid < 64) {
    int i = min(loc * 64 + tid, nt - 1);
    tkl[tid] = tlist[(size_t)e * BT + i] >> 2;
  }
  __syncthreads();   // tkl visible + stage(0) drained

  const int t0 = tkl[wn * 32 + l15];
  const int t1 = tkl[wn * 32 + 16 + l15];
  auto ldb = [&](int t, int st, int ss) {
    return *reinterpret_cast<const short8*>(
        xb + (size_t)t * 512 + st * 64 + ss * 32 + q * 8);
  };

  f32x4 acc[4][2];
#pragma unroll
  for (int a = 0; a < 4; a++)
#pragma unroll
    for (int b = 0; b < 2; b++) acc[a][b] = {0.f, 0.f, 0.f, 0.f};

  short8 bfr[2][2];  // [nf][ss]
  bfr[0][0] = ldb(t0, 0, 0); bfr[0][1] = ldb(t0, 0, 1);
  bfr[1][0] = ldb(t1, 0, 0); bfr[1][1] = ldb(t1, 0, 1);

  for (int st = 0; st < 8; ++st) {
    const u32* cur = stg[st & 1];
    short8 nb[2][2];
    if (st < 7) {
      stage(st + 1, stg[(st + 1) & 1]);
      nb[0][0] = ldb(t0, st + 1, 0); nb[0][1] = ldb(t0, st + 1, 1);
      nb[1][0] = ldb(t1, st + 1, 0); nb[1][1] = ldb(t1, st + 1, 1);
    }
#pragma unroll
    for (int ss = 0; ss < 2; ++ss) {
#pragma unroll
      for (int mf = 0; mf < 4; ++mf) {
        int col = wm * 64 + mf * 16 + l15;
        short8 af = *reinterpret_cast<const short8*>(
            cur + ss * 2048 + q * 512 + col * 4);
        acc[mf][0] = __builtin_amdgcn_mfma_f32_16x16x32_bf16(af, bfr[0][ss], acc[mf][0], 0, 0, 0);
        acc[mf][1] = __builtin_amdgcn_mfma_f32_16x16x32_bf16(af, bfr[1][ss], acc[mf][1], 0, 0, 0);
      }
    }
    __syncthreads();   // next stage drained; buffers safe to swap
    if (st < 7) {
      bfr[0][0] = nb[0][0]; bfr[0][1] = nb[0][1];
      bfr[1][0] = nb[1][0]; bfr[1][1] = nb[1][1];
    }
  }

  // epilogue: bias + relu + pack bf16 -> hid[prow][h]
  const float* b1e = b1 + (size_t)e * HH;
#pragma unroll
  for (int mf = 0; mf < 4; ++mf) {
    int h0 = hc * 128 + wm * 64 + mf * 16 + q * 4;
    float4 bb = *reinterpret_cast<const float4*>(b1e + h0);
#pragma unroll
    for (int nf = 0; nf < 2; ++nf) {
      int local = wn * 32 + nf * 16 + l15;
      int prow = c * 64 + local;
      float v0 = fmaxf(acc[mf][nf].x + bb.x, 0.f);
      float v1 = fmaxf(acc[mf][nf].y + bb.y, 0.f);
      float v2 = fmaxf(acc[mf][nf].z + bb.z, 0.f);
      float v3 = fmaxf(acc[mf][nf].w + bb.w, 0.f);
      u32x2 pk = { pack2bf(v0, v1), pack2bf(v2, v3) };
      *reinterpret_cast<u32x2*>(hid + (size_t)prow * 256 + (h0 >> 1)) = pk;
    }
  }
}

// ---------------------------------------------------------------------------
// GEMM2 (grouped, swapped): oT = W2T(512d x 512h) . hidT(512h x 64t).
// ---------------------------------------------------------------------------
__global__ __launch_bounds__(256)
void k_gemm2(const u32* __restrict__ hid, const u32* __restrict__ img,
             const float* __restrict__ b2, const int* __restrict__ cnt,
             const int* __restrict__ tlist, const int* __restrict__ chunk2e,
             const int* __restrict__ chunkloc, float* __restrict__ o_p) {
  __shared__ u32 stg[2][4096];
  __shared__ int tke[64];
  const int c = remap_chunk(blockIdx.x);
  const int e = chunk2e[c];
  if (e < 0) return;
  const int dc = blockIdx.y;
  const int loc = chunkloc[c];
  const int nt = cnt[e];
  const int tid = threadIdx.x;
  const int w = tid >> 6, lane = tid & 63;
  const int l15 = lane & 15, q = lane >> 4;
  const int wm = w & 1, wn = w >> 1;
  const int rows_c = min(64, nt - loc * 64);

  const u32* imgb = img + ((size_t)((EE + e) * 4 + dc) * 16) * 2048;
  auto stage = [&](int st, u32* dst) {
    const u32* src = imgb + st * 4096;
#pragma unroll
    for (int i = 0; i < 4; i++)
      gload_lds16(src + tid * 4 + i * 1024, dst + tid * 4 + i * 1024);
  };

  stage(0, stg[0]);
  if (tid < 64) {
    int i = min(loc * 64 + tid, nt - 1);
    tke[tid] = tlist[(size_t)e * BT + i];
  }
  __syncthreads();

  const u16* hid16 = (const u16*)hid;
  const int pr0 = c * 64 + wn * 32 + l15;
  const int pr1 = pr0 + 16;
  auto ldb = [&](int pr, int st, int ss) {
    return *reinterpret_cast<const short8*>(
        hid16 + (size_t)pr * 512 + st * 64 + ss * 32 + q * 8);
  };

  f32x4 acc[4][2];
#pragma unroll
  for (int a = 0; a < 4; a++)
#pragma unroll
    for (int b = 0; b < 2; b++) acc[a][b] = {0.f, 0.f, 0.f, 0.f};

  short8 bfr[2][2];
  bfr[0][0] = ldb(pr0, 0, 0); bfr[0][1] = ldb(pr0, 0, 1);
  bfr[1][0] = ldb(pr1, 0, 0); bfr[1][1] = ldb(pr1, 0, 1);

  for (int st = 0; st < 8; ++st) {
    const u32* cur = stg[st & 1];
    short8 nb[2][2];
    if (st < 7) {
      stage(st + 1, stg[(st + 1) & 1]);
      nb[0][0] = ldb(pr0, st + 1, 0); nb[0][1] = ldb(pr0, st + 1, 1);
      nb[1][0] = ldb(pr1, st + 1, 0); nb[1][1] = ldb(pr1, st + 1, 1);
    }
#pragma unroll
    for (int ss = 0; ss < 2; ++ss) {
#pragma unroll
      for (int mf = 0; mf < 4; ++mf) {
        int col = wm * 64 + mf * 16 + l15;
        short8 af = *reinterpret_cast<const short8*>(
            cur + ss * 2048 + q * 512 + col * 4);
        acc[mf][0] = __builtin_amdgcn_mfma_f32_16x16x32_bf16(af, bfr[0][ss], acc[mf][0], 0, 0, 0);
        acc[mf][1] = __builtin_amdgcn_mfma_f32_16x16x32_bf16(af, bfr[1][ss], acc[mf][1], 0, 0, 0);
      }
    }
    __syncthreads();
    if (st < 7) {
      bfr[0][0] = nb[0][0]; bfr[0][1] = nb[0][1];
      bfr[1][0] = nb[1][0]; bfr[1][1] = nb[1][1];
    }
  }

  // epilogue: bias + scatter fp32 to o_p[(t*K+slot)*D + d] (skip pad rows)
  const float* b2e = b2 + (size_t)e * DD;
#pragma unroll
  for (int mf = 0; mf < 4; ++mf) {
    int d0 = dc * 128 + wm * 64 + mf * 16 + q * 4;
    float4 bb = *reinterpret_cast<const float4*>(b2e + d0);
#pragma unroll
    for (int nf = 0; nf < 2; ++nf) {
      int local = wn * 32 + nf * 16 + l15;
      if (local < rows_c) {
        int ent = tke[local];
        int t = ent >> 2, sl = ent & 3;
        float4 v;
        v.x = acc[mf][nf].x + bb.x;
        v.y = acc[mf][nf].y + bb.y;
        v.z = acc[mf][nf].z + bb.z;
        v.w = acc[mf][nf].w + bb.w;
        *reinterpret_cast<float4*>(&o_p[((size_t)t * KK + sl) * DD + d0]) = v;
      }
    }
  }
}

// ---------------------------------------------------------------------------
// Confidence via MFMA. One block per 64-token chunk, 256 thr (4 waves).
// Wave w: tokens w*16 + l15; both 16-ch tiles; K=512 in 16 steps.
// Wc1e image (32 KB) staged whole; B-fragments packed on the fly from
// fp32 o_p rows. Layer2 + sigmoid via shfl reduction over q.
// ---------------------------------------------------------------------------
__global__ __launch_bounds__(256)
void k_conf2(const float* __restrict__ o_p, const u32* __restrict__ img_c,
             const float* __restrict__ bc1, const float* __restrict__ Wc2,
             const float* __restrict__ bc2, const float* __restrict__ wts,
             const int* __restrict__ cnt, const int* __restrict__ tlist,
             const int* __restrict__ chunk2e, const int* __restrict__ chunkloc,
             float* __restrict__ cw) {
  __shared__ u32 stg[8192];   // 32 KB: full Wc1e image (16 steps x 512 u32)
  __shared__ int tke[64];
  const int c = remap_chunk(blockIdx.x);
  const int e = chunk2e[c];
  if (e < 0) return;
  const int loc = chunkloc[c];
  const int nt = cnt[e];
  const int tid = threadIdx.x;
  const int w = tid >> 6, lane = tid & 63;
  const int l15 = lane & 15, q = lane >> 4;

  const u32* src = img_c + (size_t)e * 16 * 512;
#pragma unroll
  for (int i = 0; i < 8; ++i)
    gload_lds16(src + tid * 4 + i * 1024, stg + tid * 4 + i * 1024);
  if (tid < 64) {
    int i = min(loc * 64 + tid, nt - 1);
    tke[tid] = tlist[(size_t)e * BT + i];
  }
  __syncthreads();   // stage drained + tke visible

  const int rows_c = min(64, nt - loc * 64);
  const int local = w * 16 + l15;
  const int ent = tke[local];
  const float* orow = o_p + (size_t)ent * DD;   // (t*K+sl)*D == ent*512

  f32x4 acc0 = {0.f, 0.f, 0.f, 0.f}, acc1 = {0.f, 0.f, 0.f, 0.f};
#pragma unroll
  for (int st = 0; st < 16; ++st) {
    float4 f0 = *reinterpret_cast<const float4*>(orow + st * 32 + q * 8);
    float4 f1 = *reinterpret_cast<const float4*>(orow + st * 32 + q * 8 + 4);
    u32x4 bp = { pack2bf(f0.x, f0.y), pack2bf(f0.z, f0.w),
                 pack2bf(f1.x, f1.y), pack2bf(f1.z, f1.w) };
    short8 bfrag = __builtin_bit_cast(short8, bp);
    short8 af0 = *reinterpret_cast<const short8*>(
        stg + st * 512 + q * 128 + l15 * 4);
    short8 af1 = *reinterpret_cast<const short8*>(
        stg + st * 512 + q * 128 + (16 + l15) * 4);
    acc0 = __builtin_amdgcn_mfma_f32_16x16x32_bf16(af0, bfrag, acc0, 0, 0, 0);
    acc1 = __builtin_amdgcn_mfma_f32_16x16x32_bf16(af1, bfrag, acc1, 0, 0, 0);
  }

  // layer 2: ch = m2*16 + q*4 + i live in this lane's acc regs
  float part = 0.f;
#pragma unroll
  for (int i = 0; i < 4; ++i) {
    int ch0 = q * 4 + i, ch1 = 16 + q * 4 + i;
    float h0 = fmaxf(acc0[i] + bc1[(size_t)e * CHN + ch0], 0.f);
    float h1 = fmaxf(acc1[i] + bc1[(size_t)e * CHN + ch1], 0.f);
    part = fmaf(h0, Wc2[(size_t)e * CHN + ch0], part);
    part = fmaf(h1, Wc2[(size_t)e * CHN + ch1], part);
  }
  part += __shfl_xor(part, 16);
  part += __shfl_xor(part, 32);
  if (q == 0 && local < rows_c) {
    float cv = 1.f / (1.f + expf(-(part + bc2[e])));
    cw[ent] = wts[(size_t)(ent >> 2) * EE + e] * cv;
  }
}

// ---------------------------------------------------------------------------
// Combine: out[t] = sum_s cw*o / (sum_s cw + eps)
// ---------------------------------------------------------------------------
__global__ __launch_bounds__(256)
void k_combine(const float* __restrict__ o_p, const float* __restrict__ cw,
               float* __restrict__ out) {
  int gid = blockIdx.x * 256 + threadIdx.x;
  int t = gid >> 7;
  int j = gid & 127;
  float c0 = cw[t * 4 + 0], c1 = cw[t * 4 + 1];
  float c2 = cw[t * 4 + 2], c3 = cw[t * 4 + 3];
  float den = c0 + c1 + c2 + c3 + 1e-6f;
  const float4* base = reinterpret_cast<const float4*>(o_p) + (size_t)t * 4 * 128;
  float4 v0 = base[0 * 128 + j];
  float4 v1 = base[1 * 128 + j];
  float4 v2 = base[2 * 128 + j];
  float4 v3 = base[3 * 128 + j];
  float4 r;
  r.x = (c0 * v0.x + c1 * v1.x + c2 * v2.x + c3 * v3.x) / den;
  r.y = (c0 * v0.y + c1 * v1.y + c2 * v2.y + c3 * v3.y) / den;
  r.z = (c0 * v0.z + c1 * v1.z + c2 * v2.z + c3 * v3.z) / den;
  r.w = (c0 * v0.w + c1 * v1.w + c2 * v2.w + c3 * v3.w) / den;
  reinterpret_cast<float4*>(out)[gid] = r;
}

extern "C" void kernel_launch(void* const* d_in, const int* in_sizes, int n_in,
                              void* d_out, int out_size, void* d_ws, size_t ws_size,
                              hipStream_t stream) {
  const float* x   = (const float*)d_in[0];
  const float* W1  = (const float*)d_in[1];
  const float* b1  = (const float*)d_in[2];
  const float* W2  = (const float*)d_in[3];
  const float* b2  = (const float*)d_in[4];
  const float* Wg1 = (const float*)d_in[5];
  const float* bg1 = (const float*)d_in[6];
  const float* Wg2 = (const float*)d_in[7];
  const float* bg2 = (const float*)d_in[8];
  const float* Wc1 = (const float*)d_in[9];
  const float* bc1 = (const float*)d_in[10];
  const float* Wc2 = (const float*)d_in[11];
  const float* bc2 = (const float*)d_in[12];
  float* out = (float*)d_out;

  // workspace layout (~64 MB)
  char* p = (char*)d_ws;
  u16* xb = (u16*)p;            p += (size_t)BT * DD * 2;            // 2 MB
  u32* img = (u32*)p;           p += (size_t)64 * 4 * 16 * 2048 * 4; // 32 MB
  float* h_g = (float*)p;                                            // gate h (4 MB)
  u32* hid = (u32*)p;           p += (size_t)MAXCH * 64 * DD * 2;    // 10 MB (aliases h_g; disjoint in time)
  float* wts = (float*)p;       p += (size_t)BT * EE * 4;            // 256 KB
  float* cw  = (float*)p;       p += (size_t)BT * KK * 4;            // 32 KB
  float* o_p = (float*)p;       p += (size_t)BT * KK * DD * 4;       // 16 MB
  int* cnt = (int*)p;           p += 256;
  int* tlist = (int*)p;         p += (size_t)EE * BT * 4;            // 256 KB
  int* chunk2e = (int*)p;       p += 1024;
  int* chunkloc = (int*)p;      p += 1024;
  u32* img_c = (u32*)p;         p += (size_t)EE * 16 * 512 * 4;      // 1 MB

  hipMemsetAsync(cnt, 0, EE * sizeof(int), stream);
  k_cvt_x<<<(BT * DD) / (256 * 8), 256, 0, stream>>>(x, xb);
  k_tr_w<<<dim3(2, 16, 64), 256, 0, stream>>>(W1, W2, img);
  k_tr_wc<<<dim3(EE, 16), 128, 0, stream>>>(Wc1, img_c);
  k_gate_hidden<<<dim3(BT / 16, 4), 256, 0, stream>>>(x, Wg1, bg1, h_g);
  k_gate_route<<<BT / 8, 256, 0, stream>>>(h_g, Wg2, bg2, wts, cnt, tlist);
  k_scan<<<1, 32, 0, stream>>>(cnt, chunk2e, chunkloc);
  k_gemm1<<<dim3(MAXCH, 4), 256, 0, stream>>>(xb, img, b1, cnt, tlist,
                                              chunk2e, chunkloc, hid);
  k_gemm2<<<dim3(MAXCH, 4), 256, 0, stream>>>(hid, img, b2, cnt, tlist,
                                              chunk2e, chunkloc, o_p);
  k_conf2<<<MAXCH, 256, 0, stream>>>(o_p, img_c, bc1, Wc2, bc2, wts,
                                     cnt, tlist, chunk2e, chunkloc, cw);
  k_combine<<<(BT * (DD / 4)) / 256, 256, 0, stream>>>(o_p, cw, out);
}

// Round 9
// 163.916 us; speedup vs baseline: 1.3553x; 1.0172x over previous
//
#include <hip/hip_runtime.h>
#include <hip/hip_bf16.h>

// Problem constants
#define BT 2048   // batch
#define DD 512    // input dim
#define HH 512    // hidden dim
#define EE 32     // experts
#define KK 4      // top-k
#define CHN 32    // confidence hidden
#define MAXCH 160 // max 64-row chunks: 8192/64 + 32

// fused prep block ranges
#define NB_GH 512
#define NB_CVT 512
#define NB_TRWC 256
#define NB_TRW 2048
#define NB_PREP (NB_GH + NB_CVT + NB_TRWC + NB_TRW)

typedef unsigned int u32;
typedef unsigned short u16;
typedef __attribute__((ext_vector_type(8))) short short8;
typedef __attribute__((ext_vector_type(4))) float f32x4;
typedef __attribute__((ext_vector_type(2))) u32 u32x2;
typedef __attribute__((ext_vector_type(4))) u32 u32x4;

__device__ inline u16 f2bf(float f) {  // RNE float->bf16
  u32 u = __builtin_bit_cast(u32, f);
  u32 r = (u + 0x7FFFu + ((u >> 16) & 1u)) >> 16;
  return (u16)r;
}
__device__ inline u32 pack2bf(float a, float b) {
  return (u32)f2bf(a) | ((u32)f2bf(b) << 16);
}
__device__ inline void gload_lds16(const u32* g, u32* l) {
  __builtin_amdgcn_global_load_lds((const __attribute__((address_space(1))) u32*)g,
                                   (__attribute__((address_space(3))) u32*)l, 16, 0, 0);
}

// ---------------------------------------------------------------------------
// Fused prep: gate_hidden | cvt_x | tr_wc | tr_w — independent, one dispatch
// so HBM-bound weight transform overlaps VALU-bound gating GEMM.
// ---------------------------------------------------------------------------
__global__ __launch_bounds__(256, 4)
void k_prep(const float* __restrict__ x, const float* __restrict__ W1,
            const float* __restrict__ W2, const float* __restrict__ Wc1,
            const float* __restrict__ Wg1, const float* __restrict__ bg1,
            u16* __restrict__ xb, u32* __restrict__ img,
            u32* __restrict__ img_c, float* __restrict__ h) {
  const int bx = blockIdx.x;
  const int tid = threadIdx.x;
  if (bx < NB_GH) {
    // ---- gate_hidden: h = relu(x @ Wg1 + bg1), fp32 ----
    __shared__ float xs[16][DD + 4];
    const int row0 = (bx >> 2) * 16;
    const int cb = (bx & 3) * 128;
    for (int idx = tid; idx < 16 * 128; idx += 256) {
      int m = idx >> 7, j = idx & 127;
      *reinterpret_cast<float4*>(&xs[m][4 * j]) =
          *reinterpret_cast<const float4*>(&x[(size_t)(row0 + m) * DD + 4 * j]);
    }
    __syncthreads();
    const int cg = tid & 31, rg = tid >> 5;
    const int n0 = cb + cg * 4;
    const int r0 = rg * 2, r1 = r0 + 1;
    float4 a0 = {0.f, 0.f, 0.f, 0.f}, a1 = {0.f, 0.f, 0.f, 0.f};
    for (int k0 = 0; k0 < DD; k0 += 8) {
      float4 wv[8];
#pragma unroll
      for (int u = 0; u < 8; ++u)
        wv[u] = *reinterpret_cast<const float4*>(&Wg1[(size_t)(k0 + u) * HH + n0]);
#pragma unroll
      for (int u = 0; u < 8; ++u) {
        float xa = xs[r0][k0 + u], xbv = xs[r1][k0 + u];
        a0.x = fmaf(xa, wv[u].x, a0.x);
        a0.y = fmaf(xa, wv[u].y, a0.y);
        a0.z = fmaf(xa, wv[u].z, a0.z);
        a0.w = fmaf(xa, wv[u].w, a0.w);
        a1.x = fmaf(xbv, wv[u].x, a1.x);
        a1.y = fmaf(xbv, wv[u].y, a1.y);
        a1.z = fmaf(xbv, wv[u].z, a1.z);
        a1.w = fmaf(xbv, wv[u].w, a1.w);
      }
    }
    float4 bb = *reinterpret_cast<const float4*>(&bg1[n0]);
    float4 o0, o1;
    o0.x = fmaxf(a0.x + bb.x, 0.f); o0.y = fmaxf(a0.y + bb.y, 0.f);
    o0.z = fmaxf(a0.z + bb.z, 0.f); o0.w = fmaxf(a0.w + bb.w, 0.f);
    o1.x = fmaxf(a1.x + bb.x, 0.f); o1.y = fmaxf(a1.y + bb.y, 0.f);
    o1.z = fmaxf(a1.z + bb.z, 0.f); o1.w = fmaxf(a1.w + bb.w, 0.f);
    *reinterpret_cast<float4*>(&h[(size_t)(row0 + r0) * HH + n0]) = o0;
    *reinterpret_cast<float4*>(&h[(size_t)(row0 + r1) * HH + n0]) = o1;
  } else if (bx < NB_GH + NB_CVT) {
    // ---- cvt_x: x fp32 -> bf16 ----
    int gid = (bx - NB_GH) * 256 + tid;
    const float4* src = reinterpret_cast<const float4*>(x) + (size_t)gid * 2;
    float4 a = src[0], b = src[1];
    u32x4 o = { pack2bf(a.x, a.y), pack2bf(a.z, a.w),
                pack2bf(b.x, b.y), pack2bf(b.z, b.w) };
    reinterpret_cast<u32x4*>(xb)[gid] = o;
  } else if (bx < NB_GH + NB_CVT + NB_TRWC) {
    // ---- tr_wc: Wc1 -> bf16 k-major fraglet image ----
    int idx = (bx - (NB_GH + NB_CVT)) * 2 + (tid >> 7);
    int e = idx >> 4, s = idx & 15;
    int t127 = tid & 127;
    int q = t127 >> 5, col = t127 & 31;
    const float* W = Wc1 + (size_t)e * DD * CHN;
    float v[8];
#pragma unroll
    for (int j = 0; j < 8; ++j)
      v[j] = W[(size_t)(s * 32 + q * 8 + j) * CHN + col];
    u32x4 fr = { pack2bf(v[0], v[1]), pack2bf(v[2], v[3]),
                 pack2bf(v[4], v[5]), pack2bf(v[6], v[7]) };
    *reinterpret_cast<u32x4*>(img_c + ((size_t)e * 16 + s) * 512 + q * 128 + col * 4) = fr;
  } else {
    // ---- tr_w: W1/W2 -> k-major bf16 fraglet images ----
    int u = bx - (NB_GH + NB_CVT + NB_TRWC);
    int z = u >> 5;
    int s = (u >> 1) & 15;
    int n = (u & 1) * 256 + tid;
    const float* W = (z < EE) ? (W1 + (size_t)z * DD * HH)
                              : (W2 + (size_t)(z - EE) * HH * DD);
    float v[32];
#pragma unroll
    for (int k = 0; k < 32; k++)
      v[k] = W[(size_t)(s * 32 + k) * 512 + n];
    int nc = n >> 7, coll = n & 127;
    u32* ob = img + ((size_t)(z * 4 + nc) * 16 + s) * 2048 + coll * 4;
#pragma unroll
    for (int g = 0; g < 4; g++) {
      u32x4 fr = { pack2bf(v[g * 8 + 0], v[g * 8 + 1]),
                   pack2bf(v[g * 8 + 2], v[g * 8 + 3]),
                   pack2bf(v[g * 8 + 4], v[g * 8 + 5]),
                   pack2bf(v[g * 8 + 6], v[g * 8 + 7]) };
      *reinterpret_cast<u32x4*>(ob + g * 512) = fr;
    }
  }
}

// ---------------------------------------------------------------------------
// Gating logits + softmax + top-4 + routing. 512 thr (8 waves), 8 tok/block.
// One token per wave; 2-way k-split (th = lane>>5 handles 256 k's) halves the
// serial LDS-FMA chain; shfl_down(32) combines. fp32 throughout (top-k).
// ---------------------------------------------------------------------------
__global__ __launch_bounds__(512)
void k_gate_route(const float* __restrict__ h, const float* __restrict__ Wg2,
                  const float* __restrict__ bg2, float* __restrict__ wts,
                  int* __restrict__ cnt, int* __restrict__ tlist) {
  __shared__ float wg2s[HH * EE];  // 64 KB, k-major [512][32]
  __shared__ float hb[8][HH];      // 16 KB
  const int tid = threadIdx.x;
  const int t0 = blockIdx.x * 8;
#pragma unroll
  for (int i = 0; i < 8; ++i) {
    int idx = tid + i * 512;
    reinterpret_cast<float4*>(wg2s)[idx] =
        reinterpret_cast<const float4*>(Wg2)[idx];
  }
#pragma unroll
  for (int i = 0; i < 2; ++i) {
    int idx = tid + i * 512;
    int m = idx >> 7, j = idx & 127;
    *reinterpret_cast<float4*>(&hb[m][4 * j]) =
        *reinterpret_cast<const float4*>(&h[(size_t)(t0 + m) * HH + 4 * j]);
  }
  __syncthreads();
  const int wv = tid >> 6, lane = tid & 63;
  const int e = lane & 31, th = lane >> 5;
  const int t = t0 + wv;
  float ac[4] = {0.f, 0.f, 0.f, 0.f};
  const int kb = th * 256;
  for (int k0 = 0; k0 < 256; k0 += 8) {
    int k = kb + k0;
    float4 h0 = *reinterpret_cast<const float4*>(&hb[wv][k]);
    float4 h1 = *reinterpret_cast<const float4*>(&hb[wv][k + 4]);
    float hv[8] = {h0.x, h0.y, h0.z, h0.w, h1.x, h1.y, h1.z, h1.w};
#pragma unroll
    for (int u = 0; u < 8; ++u)
      ac[u & 3] = fmaf(hv[u], wg2s[(k + u) * EE + e], ac[u & 3]);
  }
  float part = ((ac[0] + ac[1]) + (ac[2] + ac[3]));
  part += __shfl_down(part, 32);     // th=1 partial into th=0 lanes
  float logit = part + bg2[e];
  // softmax + top-4 over the low 32 lanes (upper lanes compute garbage,
  // isolated by width-32 shuffles; all writes guarded to th==0).
  float mx = logit;
#pragma unroll
  for (int m = 16; m >= 1; m >>= 1) mx = fmaxf(mx, __shfl_xor(mx, m, 32));
  float ex = expf(logit - mx);
  float sm = ex;
#pragma unroll
  for (int m = 16; m >= 1; m >>= 1) sm += __shfl_xor(sm, m, 32);
  float w = ex / sm;
  if (th == 0) wts[(size_t)t * EE + e] = w;
  float wcur = w;
  for (int j = 0; j < KK; j++) {
    float v = wcur;
    int vi = e;
#pragma unroll
    for (int m = 16; m >= 1; m >>= 1) {
      float ov = __shfl_xor(v, m, 32);
      int oi = __shfl_xor(vi, m, 32);
      if (ov > v || (ov == v && oi < vi)) { v = ov; vi = oi; }
    }
    if (lane == 0) {
      int pos = atomicAdd(&cnt[vi], 1);
      tlist[(size_t)vi * BT + pos] = (t << 2) | j;
    }
    if (th == 0 && e == vi) wcur = -1.f;
  }
}

// ---------------------------------------------------------------------------
// Build chunk tables: chunk c -> (expert, local chunk index). 64 rows/chunk.
// ---------------------------------------------------------------------------
__global__ void k_scan(const int* __restrict__ cnt, int* __restrict__ chunk2e,
                       int* __restrict__ chunkloc) {
  int e = threadIdx.x;
  if (e >= EE) return;
  int off = 0, tot = 0;
  for (int j = 0; j < EE; ++j) {
    int nj = (cnt[j] + 63) >> 6;
    if (j < e) off += nj;
    tot += nj;
  }
  int myn = (cnt[e] + 63) >> 6;
  for (int j = 0; j < myn; ++j) {
    chunk2e[off + j] = e; chunkloc[off + j] = j;
  }
  for (int idx = tot + e; idx < MAXCH; idx += EE) {
    chunk2e[idx] = -1; chunkloc[idx] = 0;
  }
}

// XCD-affinity chunk remap.
__device__ inline int remap_chunk(int bx) {
  return (bx & 7) * (MAXCH / 8) + (bx >> 3);
}

// ---------------------------------------------------------------------------
// GEMM1 (grouped, swapped): hidT = W1T(512h x 512k) . xT(512k x 64t).
// ---------------------------------------------------------------------------
__global__ __launch_bounds__(256)
void k_gemm1(const u16* __restrict__ xb, const u32* __restrict__ img,
             const float* __restrict__ b1, const int* __restrict__ cnt,
             const int* __restrict__ tlist, const int* __restrict__ chunk2e,
             const int* __restrict__ chunkloc, u32* __restrict__ hid) {
  __shared__ u32 stg[2][4096];   // 2 x 16 KB
  __shared__ int tkl[64];
  const int c = remap_chunk(blockIdx.x);
  const int e = chunk2e[c];
  if (e < 0) return;
  const int hc = blockIdx.y;
  const int loc = chunkloc[c];
  const int nt = cnt[e];
  const int tid = threadIdx.x;
  const int w = tid >> 6, lane = tid & 63;
  const int l15 = lane & 15, q = lane >> 4;
  const int wm = w & 1, wn = w >> 1;

  const u32* imgb = img + ((size_t)(e * 4 + hc) * 16) * 2048;
  auto stage = [&](int st, u32* dst) {
    const u32* src = imgb + st * 4096;
#pragma unroll
    for (int i = 0; i < 4; i++)
      gload_lds16(src + tid * 4 + i * 1024, dst + tid * 4 + i * 1024);
  };

  stage(0, stg[0]);
  if (tid < 64) {
    int i = min(loc * 64 + tid, nt - 1);
    tkl[tid] = tlist[(size_t)e * BT + i] >> 2;
  }
  __syncthreads();   // tkl visible + stage(0) drained

  const int t0 = tkl[wn * 32 + l15];
  const int t1 = tkl[wn * 32 + 16 + l15];
  auto ldb = [&](int t, int st, int ss) {
    return *reinterpret_cast<const short8*>(
        xb + (size_t)t * 512 + st * 64 + ss * 32 + q * 8);
  };

  f32x4 acc[4][2];
#pragma unroll
  for (int a = 0; a < 4; a++)
#pragma unroll
    for (int b = 0; b < 2; b++) acc[a][b] = {0.f, 0.f, 0.f, 0.f};

  short8 bfr[2][2];  // [nf][ss]
  bfr[0][0] = ldb(t0, 0, 0); bfr[0][1] = ldb(t0, 0, 1);
  bfr[1][0] = ldb(t1, 0, 0); bfr[1][1] = ldb(t1, 0, 1);

  for (int st = 0; st < 8; ++st) {
    const u32* cur = stg[st & 1];
    short8 nb[2][2];
    if (st < 7) {
      stage(st + 1, stg[(st + 1) & 1]);
      nb[0][0] = ldb(t0, st + 1, 0); nb[0][1] = ldb(t0, st + 1, 1);
      nb[1][0] = ldb(t1, st + 1, 0); nb[1][1] = ldb(t1, st + 1, 1);
    }
#pragma unroll
    for (int ss = 0; ss < 2; ++ss) {
#pragma unroll
      for (int mf = 0; mf < 4; ++mf) {
        int col = wm * 64 + mf * 16 + l15;
        short8 af = *reinterpret_cast<const short8*>(
            cur + ss * 2048 + q * 512 + col * 4);
        acc[mf][0] = __builtin_amdgcn_mfma_f32_16x16x32_bf16(af, bfr[0][ss], acc[mf][0], 0, 0, 0);
        acc[mf][1] = __builtin_amdgcn_mfma_f32_16x16x32_bf16(af, bfr[1][ss], acc[mf][1], 0, 0, 0);
      }
    }
    __syncthreads();   // next stage drained; buffers safe to swap
    if (st < 7) {
      bfr[0][0] = nb[0][0]; bfr[0][1] = nb[0][1];
      bfr[1][0] = nb[1][0]; bfr[1][1] = nb[1][1];
    }
  }

  // epilogue: bias + relu + pack bf16 -> hid[prow][h]
  const float* b1e = b1 + (size_t)e * HH;
#pragma unroll
  for (int mf = 0; mf < 4; ++mf) {
    int h0 = hc * 128 + wm * 64 + mf * 16 + q * 4;
    float4 bb = *reinterpret_cast<const float4*>(b1e + h0);
#pragma unroll
    for (int nf = 0; nf < 2; ++nf) {
      int local = wn * 32 + nf * 16 + l15;
      int prow = c * 64 + local;
      float v0 = fmaxf(acc[mf][nf].x + bb.x, 0.f);
      float v1 = fmaxf(acc[mf][nf].y + bb.y, 0.f);
      float v2 = fmaxf(acc[mf][nf].z + bb.z, 0.f);
      float v3 = fmaxf(acc[mf][nf].w + bb.w, 0.f);
      u32x2 pk = { pack2bf(v0, v1), pack2bf(v2, v3) };
      *reinterpret_cast<u32x2*>(hid + (size_t)prow * 256 + (h0 >> 1)) = pk;
    }
  }
}

// ---------------------------------------------------------------------------
// GEMM2 (grouped, swapped): oT = W2T(512d x 512h) . hidT(512h x 64t).
// ---------------------------------------------------------------------------
__global__ __launch_bounds__(256)
void k_gemm2(const u32* __restrict__ hid, const u32* __restrict__ img,
             const float* __restrict__ b2, const int* __restrict__ cnt,
             const int* __restrict__ tlist, const int* __restrict__ chunk2e,
             const int* __restrict__ chunkloc, float* __restrict__ o_p) {
  __shared__ u32 stg[2][4096];
  __shared__ int tke[64];
  const int c = remap_chunk(blockIdx.x);
  const int e = chunk2e[c];
  if (e < 0) return;
  const int dc = blockIdx.y;
  const int loc = chunkloc[c];
  const int nt = cnt[e];
  const int tid = threadIdx.x;
  const int w = tid >> 6, lane = tid & 63;
  const int l15 = lane & 15, q = lane >> 4;
  const int wm = w & 1, wn = w >> 1;
  const int rows_c = min(64, nt - loc * 64);

  const u32* imgb = img + ((size_t)((EE + e) * 4 + dc) * 16) * 2048;
  auto stage = [&](int st, u32* dst) {
    const u32* src = imgb + st * 4096;
#pragma unroll
    for (int i = 0; i < 4; i++)
      gload_lds16(src + tid * 4 + i * 1024, dst + tid * 4 + i * 1024);
  };

  stage(0, stg[0]);
  if (tid < 64) {
    int i = min(loc * 64 + tid, nt - 1);
    tke[tid] = tlist[(size_t)e * BT + i];
  }
  __syncthreads();

  const u16* hid16 = (const u16*)hid;
  const int pr0 = c * 64 + wn * 32 + l15;
  const int pr1 = pr0 + 16;
  auto ldb = [&](int pr, int st, int ss) {
    return *reinterpret_cast<const short8*>(
        hid16 + (size_t)pr * 512 + st * 64 + ss * 32 + q * 8);
  };

  f32x4 acc[4][2];
#pragma unroll
  for (int a = 0; a < 4; a++)
#pragma unroll
    for (int b = 0; b < 2; b++) acc[a][b] = {0.f, 0.f, 0.f, 0.f};

  short8 bfr[2][2];
  bfr[0][0] = ldb(pr0, 0, 0); bfr[0][1] = ldb(pr0, 0, 1);
  bfr[1][0] = ldb(pr1, 0, 0); bfr[1][1] = ldb(pr1, 0, 1);

  for (int st = 0; st < 8; ++st) {
    const u32* cur = stg[st & 1];
    short8 nb[2][2];
    if (st < 7) {
      stage(st + 1, stg[(st + 1) & 1]);
      nb[0][0] = ldb(pr0, st + 1, 0); nb[0][1] = ldb(pr0, st + 1, 1);
      nb[1][0] = ldb(pr1, st + 1, 0); nb[1][1] = ldb(pr1, st + 1, 1);
    }
#pragma unroll
    for (int ss = 0; ss < 2; ++ss) {
#pragma unroll
      for (int mf = 0; mf < 4; ++mf) {
        int col = wm * 64 + mf * 16 + l15;
        short8 af = *reinterpret_cast<const short8*>(
            cur + ss * 2048 + q * 512 + col * 4);
        acc[mf][0] = __builtin_amdgcn_mfma_f32_16x16x32_bf16(af, bfr[0][ss], acc[mf][0], 0, 0, 0);
        acc[mf][1] = __builtin_amdgcn_mfma_f32_16x16x32_bf16(af, bfr[1][ss], acc[mf][1], 0, 0, 0);
      }
    }
    __syncthreads();
    if (st < 7) {
      bfr[0][0] = nb[0][0]; bfr[0][1] = nb[0][1];
      bfr[1][0] = nb[1][0]; bfr[1][1] = nb[1][1];
    }
  }

  // epilogue: bias + scatter fp32 to o_p[(t*K+slot)*D + d] (skip pad rows)
  const float* b2e = b2 + (size_t)e * DD;
#pragma unroll
  for (int mf = 0; mf < 4; ++mf) {
    int d0 = dc * 128 + wm * 64 + mf * 16 + q * 4;
    float4 bb = *reinterpret_cast<const float4*>(b2e + d0);
#pragma unroll
    for (int nf = 0; nf < 2; ++nf) {
      int local = wn * 32 + nf * 16 + l15;
      if (local < rows_c) {
        int ent = tke[local];
        int t = ent >> 2, sl = ent & 3;
        float4 v;
        v.x = acc[mf][nf].x + bb.x;
        v.y = acc[mf][nf].y + bb.y;
        v.z = acc[mf][nf].z + bb.z;
        v.w = acc[mf][nf].w + bb.w;
        *reinterpret_cast<float4*>(&o_p[((size_t)t * KK + sl) * DD + d0]) = v;
      }
    }
  }
}

// ---------------------------------------------------------------------------
// Confidence via MFMA. One block per 64-token chunk, 256 thr (4 waves).
// ---------------------------------------------------------------------------
__global__ __launch_bounds__(256)
void k_conf2(const float* __restrict__ o_p, const u32* __restrict__ img_c,
             const float* __restrict__ bc1, const float* __restrict__ Wc2,
             const float* __restrict__ bc2, const float* __restrict__ wts,
             const int* __restrict__ cnt, const int* __restrict__ tlist,
             const int* __restrict__ chunk2e, const int* __restrict__ chunkloc,
             float* __restrict__ cw) {
  __shared__ u32 stg[8192];   // 32 KB: full Wc1e image (16 steps x 512 u32)
  __shared__ int tke[64];
  const int c = remap_chunk(blockIdx.x);
  const int e = chunk2e[c];
  if (e < 0) return;
  const int loc = chunkloc[c];
  const int nt = cnt[e];
  const int tid = threadIdx.x;
  const int w = tid >> 6, lane = tid & 63;
  const int l15 = lane & 15, q = lane >> 4;

  const u32* src = img_c + (size_t)e * 16 * 512;
#pragma unroll
  for (int i = 0; i < 8; ++i)
    gload_lds16(src + tid * 4 + i * 1024, stg + tid * 4 + i * 1024);
  if (tid < 64) {
    int i = min(loc * 64 + tid, nt - 1);
    tke[tid] = tlist[(size_t)e * BT + i];
  }
  __syncthreads();   // stage drained + tke visible

  const int rows_c = min(64, nt - loc * 64);
  const int local = w * 16 + l15;
  const int ent = tke[local];
  const float* orow = o_p + (size_t)ent * DD;

  f32x4 acc0 = {0.f, 0.f, 0.f, 0.f}, acc1 = {0.f, 0.f, 0.f, 0.f};
#pragma unroll
  for (int st = 0; st < 16; ++st) {
    float4 f0 = *reinterpret_cast<const float4*>(orow + st * 32 + q * 8);
    float4 f1 = *reinterpret_cast<const float4*>(orow + st * 32 + q * 8 + 4);
    u32x4 bp = { pack2bf(f0.x, f0.y), pack2bf(f0.z, f0.w),
                 pack2bf(f1.x, f1.y), pack2bf(f1.z, f1.w) };
    short8 bfrag = __builtin_bit_cast(short8, bp);
    short8 af0 = *reinterpret_cast<const short8*>(
        stg + st * 512 + q * 128 + l15 * 4);
    short8 af1 = *reinterpret_cast<const short8*>(
        stg + st * 512 + q * 128 + (16 + l15) * 4);
    acc0 = __builtin_amdgcn_mfma_f32_16x16x32_bf16(af0, bfrag, acc0, 0, 0, 0);
    acc1 = __builtin_amdgcn_mfma_f32_16x16x32_bf16(af1, bfrag, acc1, 0, 0, 0);
  }

  float part = 0.f;
#pragma unroll
  for (int i = 0; i < 4; ++i) {
    int ch0 = q * 4 + i, ch1 = 16 + q * 4 + i;
    float h0 = fmaxf(acc0[i] + bc1[(size_t)e * CHN + ch0], 0.f);
    float h1 = fmaxf(acc1[i] + bc1[(size_t)e * CHN + ch1], 0.f);
    part = fmaf(h0, Wc2[(size_t)e * CHN + ch0], part);
    part = fmaf(h1, Wc2[(size_t)e * CHN + ch1], part);
  }
  part += __shfl_xor(part, 16);
  part += __shfl_xor(part, 32);
  if (q == 0 && local < rows_c) {
    float cv = 1.f / (1.f + expf(-(part + bc2[e])));
    cw[ent] = wts[(size_t)(ent >> 2) * EE + e] * cv;
  }
}

// ---------------------------------------------------------------------------
// Combine: out[t] = sum_s cw*o / (sum_s cw + eps)
// ---------------------------------------------------------------------------
__global__ __launch_bounds__(256)
void k_combine(const float* __restrict__ o_p, const float* __restrict__ cw,
               float* __restrict__ out) {
  int gid = blockIdx.x * 256 + threadIdx.x;
  int t = gid >> 7;
  int j = gid & 127;
  float c0 = cw[t * 4 + 0], c1 = cw[t * 4 + 1];
  float c2 = cw[t * 4 + 2], c3 = cw[t * 4 + 3];
  float den = c0 + c1 + c2 + c3 + 1e-6f;
  const float4* base = reinterpret_cast<const float4*>(o_p) + (size_t)t * 4 * 128;
  float4 v0 = base[0 * 128 + j];
  float4 v1 = base[1 * 128 + j];
  float4 v2 = base[2 * 128 + j];
  float4 v3 = base[3 * 128 + j];
  float4 r;
  r.x = (c0 * v0.x + c1 * v1.x + c2 * v2.x + c3 * v3.x) / den;
  r.y = (c0 * v0.y + c1 * v1.y + c2 * v2.y + c3 * v3.y) / den;
  r.z = (c0 * v0.z + c1 * v1.z + c2 * v2.z + c3 * v3.z) / den;
  r.w = (c0 * v0.w + c1 * v1.w + c2 * v2.w + c3 * v3.w) / den;
  reinterpret_cast<float4*>(out)[gid] = r;
}

extern "C" void kernel_launch(void* const* d_in, const int* in_sizes, int n_in,
                              void* d_out, int out_size, void* d_ws, size_t ws_size,
                              hipStream_t stream) {
  const float* x   = (const float*)d_in[0];
  const float* W1  = (const float*)d_in[1];
  const float* b1  = (const float*)d_in[2];
  const float* W2  = (const float*)d_in[3];
  const float* b2  = (const float*)d_in[4];
  const float* Wg1 = (const float*)d_in[5];
  const float* bg1 = (const float*)d_in[6];
  const float* Wg2 = (const float*)d_in[7];
  const float* bg2 = (const float*)d_in[8];
  const float* Wc1 = (const float*)d_in[9];
  const float* bc1 = (const float*)d_in[10];
  const float* Wc2 = (const float*)d_in[11];
  const float* bc2 = (const float*)d_in[12];
  float* out = (float*)d_out;

  // workspace layout (~64 MB)
  char* p = (char*)d_ws;
  u16* xb = (u16*)p;            p += (size_t)BT * DD * 2;            // 2 MB
  u32* img = (u32*)p;           p += (size_t)64 * 4 * 16 * 2048 * 4; // 32 MB
  float* h_g = (float*)p;                                            // gate h (4 MB)
  u32* hid = (u32*)p;           p += (size_t)MAXCH * 64 * DD * 2;    // 10 MB (aliases h_g; disjoint in time)
  float* wts = (float*)p;       p += (size_t)BT * EE * 4;            // 256 KB
  float* cw  = (float*)p;       p += (size_t)BT * KK * 4;            // 32 KB
  float* o_p = (float*)p;       p += (size_t)BT * KK * DD * 4;       // 16 MB
  int* cnt = (int*)p;           p += 256;
  int* tlist = (int*)p;         p += (size_t)EE * BT * 4;            // 256 KB
  int* chunk2e = (int*)p;       p += 1024;
  int* chunkloc = (int*)p;      p += 1024;
  u32* img_c = (u32*)p;         p += (size_t)EE * 16 * 512 * 4;      // 1 MB

  hipMemsetAsync(cnt, 0, EE * sizeof(int), stream);
  k_prep<<<NB_PREP, 256, 0, stream>>>(x, W1, W2, Wc1, Wg1, bg1,
                                      xb, img, img_c, h_g);
  k_gate_route<<<BT / 8, 512, 0, stream>>>(h_g, Wg2, bg2, wts, cnt, tlist);
  k_scan<<<1, 32, 0, stream>>>(cnt, chunk2e, chunkloc);
  k_gemm1<<<dim3(MAXCH, 4), 256, 0, stream>>>(xb, img, b1, cnt, tlist,
                                              chunk2e, chunkloc, hid);
  k_gemm2<<<dim3(MAXCH, 4), 256, 0, stream>>>(hid, img, b2, cnt, tlist,
                                              chunk2e, chunkloc, o_p);
  k_conf2<<<MAXCH, 256, 0, stream>>>(o_p, img_c, bc1, Wc2, bc2, wts,
                                     cnt, tlist, chunk2e, chunkloc, cw);
  k_combine<<<(BT * (DD / 4)) / 256, 256, 0, stream>>>(o_p, cw, out);
}

// Round 10
// 113.745 us; speedup vs baseline: 1.9531x; 1.4411x over previous
//
#include <hip/hip_runtime.h>
#include <hip/hip_bf16.h>

// Problem constants
#define BT 2048   // batch
#define DD 512    // input dim
#define HH 512    // hidden dim
#define EE 32     // experts
#define KK 4      // top-k
#define CHN 32    // confidence hidden
#define MAXCH 160 // max 64-row chunks: 8192/64 + 32

// fused prep block ranges
#define NB_GH 512
#define NB_CVT 512
#define NB_TRWC 256
#define NB_TRW 2048
#define NB_PREP (NB_GH + NB_CVT + NB_TRWC + NB_TRW)

typedef unsigned int u32;
typedef unsigned short u16;
typedef __attribute__((ext_vector_type(8))) short short8;
typedef __attribute__((ext_vector_type(4))) float f32x4;
typedef __attribute__((ext_vector_type(2))) u32 u32x2;
typedef __attribute__((ext_vector_type(4))) u32 u32x4;

__device__ inline u16 f2bf(float f) {  // RNE float->bf16
  u32 u = __builtin_bit_cast(u32, f);
  u32 r = (u + 0x7FFFu + ((u >> 16) & 1u)) >> 16;
  return (u16)r;
}
__device__ inline u32 pack2bf(float a, float b) {
  return (u32)f2bf(a) | ((u32)f2bf(b) << 16);
}
__device__ inline void gload_lds16(const u32* g, u32* l) {
  __builtin_amdgcn_global_load_lds((const __attribute__((address_space(1))) u32*)g,
                                   (__attribute__((address_space(3))) u32*)l, 16, 0, 0);
}

// ---------------------------------------------------------------------------
// Fused prep: gate_hidden | cvt_x | tr_wc | tr_w — independent, one dispatch.
// ---------------------------------------------------------------------------
__global__ __launch_bounds__(256, 4)
void k_prep(const float* __restrict__ x, const float* __restrict__ W1,
            const float* __restrict__ W2, const float* __restrict__ Wc1,
            const float* __restrict__ Wg1, const float* __restrict__ bg1,
            u16* __restrict__ xb, u32* __restrict__ img,
            u32* __restrict__ img_c, float* __restrict__ h) {
  const int bx = blockIdx.x;
  const int tid = threadIdx.x;
  if (bx < NB_GH) {
    // ---- gate_hidden: h = relu(x @ Wg1 + bg1), fp32 ----
    __shared__ float xs[16][DD + 4];
    const int row0 = (bx >> 2) * 16;
    const int cb = (bx & 3) * 128;
    for (int idx = tid; idx < 16 * 128; idx += 256) {
      int m = idx >> 7, j = idx & 127;
      *reinterpret_cast<float4*>(&xs[m][4 * j]) =
          *reinterpret_cast<const float4*>(&x[(size_t)(row0 + m) * DD + 4 * j]);
    }
    __syncthreads();
    const int cg = tid & 31, rg = tid >> 5;
    const int n0 = cb + cg * 4;
    const int r0 = rg * 2, r1 = r0 + 1;
    float4 a0 = {0.f, 0.f, 0.f, 0.f}, a1 = {0.f, 0.f, 0.f, 0.f};
    for (int k0 = 0; k0 < DD; k0 += 8) {
      float4 wv[8];
#pragma unroll
      for (int u = 0; u < 8; ++u)
        wv[u] = *reinterpret_cast<const float4*>(&Wg1[(size_t)(k0 + u) * HH + n0]);
#pragma unroll
      for (int u = 0; u < 8; ++u) {
        float xa = xs[r0][k0 + u], xbv = xs[r1][k0 + u];
        a0.x = fmaf(xa, wv[u].x, a0.x);
        a0.y = fmaf(xa, wv[u].y, a0.y);
        a0.z = fmaf(xa, wv[u].z, a0.z);
        a0.w = fmaf(xa, wv[u].w, a0.w);
        a1.x = fmaf(xbv, wv[u].x, a1.x);
        a1.y = fmaf(xbv, wv[u].y, a1.y);
        a1.z = fmaf(xbv, wv[u].z, a1.z);
        a1.w = fmaf(xbv, wv[u].w, a1.w);
      }
    }
    float4 bb = *reinterpret_cast<const float4*>(&bg1[n0]);
    float4 o0, o1;
    o0.x = fmaxf(a0.x + bb.x, 0.f); o0.y = fmaxf(a0.y + bb.y, 0.f);
    o0.z = fmaxf(a0.z + bb.z, 0.f); o0.w = fmaxf(a0.w + bb.w, 0.f);
    o1.x = fmaxf(a1.x + bb.x, 0.f); o1.y = fmaxf(a1.y + bb.y, 0.f);
    o1.z = fmaxf(a1.z + bb.z, 0.f); o1.w = fmaxf(a1.w + bb.w, 0.f);
    *reinterpret_cast<float4*>(&h[(size_t)(row0 + r0) * HH + n0]) = o0;
    *reinterpret_cast<float4*>(&h[(size_t)(row0 + r1) * HH + n0]) = o1;
  } else if (bx < NB_GH + NB_CVT) {
    // ---- cvt_x: x fp32 -> bf16 ----
    int gid = (bx - NB_GH) * 256 + tid;
    const float4* src = reinterpret_cast<const float4*>(x) + (size_t)gid * 2;
    float4 a = src[0], b = src[1];
    u32x4 o = { pack2bf(a.x, a.y), pack2bf(a.z, a.w),
                pack2bf(b.x, b.y), pack2bf(b.z, b.w) };
    reinterpret_cast<u32x4*>(xb)[gid] = o;
  } else if (bx < NB_GH + NB_CVT + NB_TRWC) {
    // ---- tr_wc: Wc1 -> bf16 k-major fraglet image ----
    int idx = (bx - (NB_GH + NB_CVT)) * 2 + (tid >> 7);
    int e = idx >> 4, s = idx & 15;
    int t127 = tid & 127;
    int q = t127 >> 5, col = t127 & 31;
    const float* W = Wc1 + (size_t)e * DD * CHN;
    float v[8];
#pragma unroll
    for (int j = 0; j < 8; ++j)
      v[j] = W[(size_t)(s * 32 + q * 8 + j) * CHN + col];
    u32x4 fr = { pack2bf(v[0], v[1]), pack2bf(v[2], v[3]),
                 pack2bf(v[4], v[5]), pack2bf(v[6], v[7]) };
    *reinterpret_cast<u32x4*>(img_c + ((size_t)e * 16 + s) * 512 + q * 128 + col * 4) = fr;
  } else {
    // ---- tr_w: W1/W2 -> k-major bf16 fraglet images ----
    int u = bx - (NB_GH + NB_CVT + NB_TRWC);
    int z = u >> 5;
    int s = (u >> 1) & 15;
    int n = (u & 1) * 256 + tid;
    const float* W = (z < EE) ? (W1 + (size_t)z * DD * HH)
                              : (W2 + (size_t)(z - EE) * HH * DD);
    float v[32];
#pragma unroll
    for (int k = 0; k < 32; k++)
      v[k] = W[(size_t)(s * 32 + k) * 512 + n];
    int nc = n >> 7, coll = n & 127;
    u32* ob = img + ((size_t)(z * 4 + nc) * 16 + s) * 2048 + coll * 4;
#pragma unroll
    for (int g = 0; g < 4; g++) {
      u32x4 fr = { pack2bf(v[g * 8 + 0], v[g * 8 + 1]),
                   pack2bf(v[g * 8 + 2], v[g * 8 + 3]),
                   pack2bf(v[g * 8 + 4], v[g * 8 + 5]),
                   pack2bf(v[g * 8 + 6], v[g * 8 + 7]) };
      *reinterpret_cast<u32x4*>(ob + g * 512) = fr;
    }
  }
}

// ---------------------------------------------------------------------------
// Gating logits + softmax + top-4. 8 tokens/block, 256 thr. NO atomics:
// writes wts[B][E] and topi[B][K] only; tlist built by k_build.
// ---------------------------------------------------------------------------
__global__ __launch_bounds__(256)
void k_gate_route(const float* __restrict__ h, const float* __restrict__ Wg2,
                  const float* __restrict__ bg2, float* __restrict__ wts,
                  int* __restrict__ topi) {
  __shared__ float wg2s[HH * EE];  // 64 KB, k-major [512][32]
  __shared__ float hb[8][HH];      // 16 KB
  const int tid = threadIdx.x;
  const int t0 = blockIdx.x * 8;
#pragma unroll
  for (int i = 0; i < 16; ++i) {
    int idx = tid + i * 256;       // float4 index, 4096 total
    reinterpret_cast<float4*>(wg2s)[idx] =
        reinterpret_cast<const float4*>(Wg2)[idx];
  }
  for (int idx = tid; idx < 8 * 128; idx += 256) {
    int m = idx >> 7, j = idx & 127;
    *reinterpret_cast<float4*>(&hb[m][4 * j]) =
        *reinterpret_cast<const float4*>(&h[(size_t)(t0 + m) * HH + 4 * j]);
  }
  __syncthreads();
  const int lane = tid & 63, wv = tid >> 6;
  const int e = lane & 31, th = lane >> 5;
  const int lt = wv * 2 + th;          // local token 0..7
  const int t = t0 + lt;
  float ac[4] = {0.f, 0.f, 0.f, 0.f};
  for (int k0 = 0; k0 < HH; k0 += 8) {
    float4 h0 = *reinterpret_cast<const float4*>(&hb[lt][k0]);
    float4 h1 = *reinterpret_cast<const float4*>(&hb[lt][k0 + 4]);
    float hv[8] = {h0.x, h0.y, h0.z, h0.w, h1.x, h1.y, h1.z, h1.w};
#pragma unroll
    for (int u = 0; u < 8; ++u)
      ac[u & 3] = fmaf(hv[u], wg2s[(k0 + u) * EE + e], ac[u & 3]);
  }
  float logit = ((ac[0] + ac[1]) + (ac[2] + ac[3])) + bg2[e];
  // softmax over the 32-lane group
  float mx = logit;
#pragma unroll
  for (int m = 16; m >= 1; m >>= 1) mx = fmaxf(mx, __shfl_xor(mx, m, 32));
  float ex = expf(logit - mx);
  float sm = ex;
#pragma unroll
  for (int m = 16; m >= 1; m >>= 1) sm += __shfl_xor(sm, m, 32);
  float w = ex / sm;
  wts[(size_t)t * EE + e] = w;
  float wcur = w;
  for (int j = 0; j < KK; j++) {
    float v = wcur;
    int vi = e;
#pragma unroll
    for (int m = 16; m >= 1; m >>= 1) {
      float ov = __shfl_xor(v, m, 32);
      int oi = __shfl_xor(vi, m, 32);
      if (ov > v || (ov == v && oi < vi)) { v = ov; vi = oi; }
    }
    if (e == 0) topi[(t << 2) | j] = vi;
    if (e == vi) wcur = -1.f;
  }
}

// ---------------------------------------------------------------------------
// Build routing lists + chunk tables from topi. One block, 1024 thr.
// LDS-atomic histogram (32 counters, one bank each) -> positions; output
// order within an expert varies but per-token math is order-independent,
// so d_out stays deterministic.
// ---------------------------------------------------------------------------
__global__ __launch_bounds__(1024)
void k_build(const int* __restrict__ topi, int* __restrict__ cnt,
             int* __restrict__ tlist, int* __restrict__ chunk2e,
             int* __restrict__ chunkloc) {
  __shared__ int lcnt[EE];
  const int tid = threadIdx.x;
  if (tid < EE) lcnt[tid] = 0;
  __syncthreads();
  for (int i = tid; i < BT * KK; i += 1024) {
    int e = topi[i];
    int pos = atomicAdd(&lcnt[e], 1);
    tlist[(size_t)e * BT + pos] = i;   // ent == (t<<2)|j == i
  }
  __syncthreads();
  if (tid < EE) {
    int e = tid;
    cnt[e] = lcnt[e];
    int off = 0, tot = 0;
    for (int j = 0; j < EE; ++j) {
      int nj = (lcnt[j] + 63) >> 6;
      if (j < e) off += nj;
      tot += nj;
    }
    int myn = (lcnt[e] + 63) >> 6;
    for (int j = 0; j < myn; ++j) {
      chunk2e[off + j] = e; chunkloc[off + j] = j;
    }
    for (int idx = tot + e; idx < MAXCH; idx += EE) {
      chunk2e[idx] = -1; chunkloc[idx] = 0;
    }
  }
}

// XCD-affinity chunk remap.
__device__ inline int remap_chunk(int bx) {
  return (bx & 7) * (MAXCH / 8) + (bx >> 3);
}

// ---------------------------------------------------------------------------
// GEMM1 (grouped, swapped): hidT = W1T(512h x 512k) . xT(512k x 64t).
// ---------------------------------------------------------------------------
__global__ __launch_bounds__(256)
void k_gemm1(const u16* __restrict__ xb, const u32* __restrict__ img,
             const float* __restrict__ b1, const int* __restrict__ cnt,
             const int* __restrict__ tlist, const int* __restrict__ chunk2e,
             const int* __restrict__ chunkloc, u32* __restrict__ hid) {
  __shared__ u32 stg[2][4096];   // 2 x 16 KB
  __shared__ int tkl[64];
  const int c = remap_chunk(blockIdx.x);
  const int e = chunk2e[c];
  if (e < 0) return;
  const int hc = blockIdx.y;
  const int loc = chunkloc[c];
  const int nt = cnt[e];
  const int tid = threadIdx.x;
  const int w = tid >> 6, lane = tid & 63;
  const int l15 = lane & 15, q = lane >> 4;
  const int wm = w & 1, wn = w >> 1;

  const u32* imgb = img + ((size_t)(e * 4 + hc) * 16) * 2048;
  auto stage = [&](int st, u32* dst) {
    const u32* src = imgb + st * 4096;
#pragma unroll
    for (int i = 0; i < 4; i++)
      gload_lds16(src + tid * 4 + i * 1024, dst + tid * 4 + i * 1024);
  };

  stage(0, stg[0]);
  if (tid < 64) {
    int i = min(loc * 64 + tid, nt - 1);
    tkl[tid] = tlist[(size_t)e * BT + i] >> 2;
  }
  __syncthreads();   // tkl visible + stage(0) drained

  const int t0 = tkl[wn * 32 + l15];
  const int t1 = tkl[wn * 32 + 16 + l15];
  auto ldb = [&](int t, int st, int ss) {
    return *reinterpret_cast<const short8*>(
        xb + (size_t)t * 512 + st * 64 + ss * 32 + q * 8);
  };

  f32x4 acc[4][2];
#pragma unroll
  for (int a = 0; a < 4; a++)
#pragma unroll
    for (int b = 0; b < 2; b++) acc[a][b] = {0.f, 0.f, 0.f, 0.f};

  short8 bfr[2][2];  // [nf][ss]
  bfr[0][0] = ldb(t0, 0, 0); bfr[0][1] = ldb(t0, 0, 1);
  bfr[1][0] = ldb(t1, 0, 0); bfr[1][1] = ldb(t1, 0, 1);

  for (int st = 0; st < 8; ++st) {
    const u32* cur = stg[st & 1];
    short8 nb[2][2];
    if (st < 7) {
      stage(st + 1, stg[(st + 1) & 1]);
      nb[0][0] = ldb(t0, st + 1, 0); nb[0][1] = ldb(t0, st + 1, 1);
      nb[1][0] = ldb(t1, st + 1, 0); nb[1][1] = ldb(t1, st + 1, 1);
    }
#pragma unroll
    for (int ss = 0; ss < 2; ++ss) {
#pragma unroll
      for (int mf = 0; mf < 4; ++mf) {
        int col = wm * 64 + mf * 16 + l15;
        short8 af = *reinterpret_cast<const short8*>(
            cur + ss * 2048 + q * 512 + col * 4);
        acc[mf][0] = __builtin_amdgcn_mfma_f32_16x16x32_bf16(af, bfr[0][ss], acc[mf][0], 0, 0, 0);
        acc[mf][1] = __builtin_amdgcn_mfma_f32_16x16x32_bf16(af, bfr[1][ss], acc[mf][1], 0, 0, 0);
      }
    }
    __syncthreads();   // next stage drained; buffers safe to swap
    if (st < 7) {
      bfr[0][0] = nb[0][0]; bfr[0][1] = nb[0][1];
      bfr[1][0] = nb[1][0]; bfr[1][1] = nb[1][1];
    }
  }

  // epilogue: bias + relu + pack bf16 -> hid[prow][h]
  const float* b1e = b1 + (size_t)e * HH;
#pragma unroll
  for (int mf = 0; mf < 4; ++mf) {
    int h0 = hc * 128 + wm * 64 + mf * 16 + q * 4;
    float4 bb = *reinterpret_cast<const float4*>(b1e + h0);
#pragma unroll
    for (int nf = 0; nf < 2; ++nf) {
      int local = wn * 32 + nf * 16 + l15;
      int prow = c * 64 + local;
      float v0 = fmaxf(acc[mf][nf].x + bb.x, 0.f);
      float v1 = fmaxf(acc[mf][nf].y + bb.y, 0.f);
      float v2 = fmaxf(acc[mf][nf].z + bb.z, 0.f);
      float v3 = fmaxf(acc[mf][nf].w + bb.w, 0.f);
      u32x2 pk = { pack2bf(v0, v1), pack2bf(v2, v3) };
      *reinterpret_cast<u32x2*>(hid + (size_t)prow * 256 + (h0 >> 1)) = pk;
    }
  }
}

// ---------------------------------------------------------------------------
// GEMM2 (grouped, swapped): oT = W2T(512d x 512h) . hidT(512h x 64t).
// ---------------------------------------------------------------------------
__global__ __launch_bounds__(256)
void k_gemm2(const u32* __restrict__ hid, const u32* __restrict__ img,
             const float* __restrict__ b2, const int* __restrict__ cnt,
             const int* __restrict__ tlist, const int* __restrict__ chunk2e,
             const int* __restrict__ chunkloc, float* __restrict__ o_p) {
  __shared__ u32 stg[2][4096];
  __shared__ int tke[64];
  const int c = remap_chunk(blockIdx.x);
  const int e = chunk2e[c];
  if (e < 0) return;
  const int dc = blockIdx.y;
  const int loc = chunkloc[c];
  const int nt = cnt[e];
  const int tid = threadIdx.x;
  const int w = tid >> 6, lane = tid & 63;
  const int l15 = lane & 15, q = lane >> 4;
  const int wm = w & 1, wn = w >> 1;
  const int rows_c = min(64, nt - loc * 64);

  const u32* imgb = img + ((size_t)((EE + e) * 4 + dc) * 16) * 2048;
  auto stage = [&](int st, u32* dst) {
    const u32* src = imgb + st * 4096;
#pragma unroll
    for (int i = 0; i < 4; i++)
      gload_lds16(src + tid * 4 + i * 1024, dst + tid * 4 + i * 1024);
  };

  stage(0, stg[0]);
  if (tid < 64) {
    int i = min(loc * 64 + tid, nt - 1);
    tke[tid] = tlist[(size_t)e * BT + i];
  }
  __syncthreads();

  const u16* hid16 = (const u16*)hid;
  const int pr0 = c * 64 + wn * 32 + l15;
  const int pr1 = pr0 + 16;
  auto ldb = [&](int pr, int st, int ss) {
    return *reinterpret_cast<const short8*>(
        hid16 + (size_t)pr * 512 + st * 64 + ss * 32 + q * 8);
  };

  f32x4 acc[4][2];
#pragma unroll
  for (int a = 0; a < 4; a++)
#pragma unroll
    for (int b = 0; b < 2; b++) acc[a][b] = {0.f, 0.f, 0.f, 0.f};

  short8 bfr[2][2];
  bfr[0][0] = ldb(pr0, 0, 0); bfr[0][1] = ldb(pr0, 0, 1);
  bfr[1][0] = ldb(pr1, 0, 0); bfr[1][1] = ldb(pr1, 0, 1);

  for (int st = 0; st < 8; ++st) {
    const u32* cur = stg[st & 1];
    short8 nb[2][2];
    if (st < 7) {
      stage(st + 1, stg[(st + 1) & 1]);
      nb[0][0] = ldb(pr0, st + 1, 0); nb[0][1] = ldb(pr0, st + 1, 1);
      nb[1][0] = ldb(pr1, st + 1, 0); nb[1][1] = ldb(pr1, st + 1, 1);
    }
#pragma unroll
    for (int ss = 0; ss < 2; ++ss) {
#pragma unroll
      for (int mf = 0; mf < 4; ++mf) {
        int col = wm * 64 + mf * 16 + l15;
        short8 af = *reinterpret_cast<const short8*>(
            cur + ss * 2048 + q * 512 + col * 4);
        acc[mf][0] = __builtin_amdgcn_mfma_f32_16x16x32_bf16(af, bfr[0][ss], acc[mf][0], 0, 0, 0);
        acc[mf][1] = __builtin_amdgcn_mfma_f32_16x16x32_bf16(af, bfr[1][ss], acc[mf][1], 0, 0, 0);
      }
    }
    __syncthreads();
    if (st < 7) {
      bfr[0][0] = nb[0][0]; bfr[0][1] = nb[0][1];
      bfr[1][0] = nb[1][0]; bfr[1][1] = nb[1][1];
    }
  }

  // epilogue: bias + scatter fp32 to o_p[(t*K+slot)*D + d] (skip pad rows)
  const float* b2e = b2 + (size_t)e * DD;
#pragma unroll
  for (int mf = 0; mf < 4; ++mf) {
    int d0 = dc * 128 + wm * 64 + mf * 16 + q * 4;
    float4 bb = *reinterpret_cast<const float4*>(b2e + d0);
#pragma unroll
    for (int nf = 0; nf < 2; ++nf) {
      int local = wn * 32 + nf * 16 + l15;
      if (local < rows_c) {
        int ent = tke[local];
        int t = ent >> 2, sl = ent & 3;
        float4 v;
        v.x = acc[mf][nf].x + bb.x;
        v.y = acc[mf][nf].y + bb.y;
        v.z = acc[mf][nf].z + bb.z;
        v.w = acc[mf][nf].w + bb.w;
        *reinterpret_cast<float4*>(&o_p[((size_t)t * KK + sl) * DD + d0]) = v;
      }
    }
  }
}

// ---------------------------------------------------------------------------
// Confidence via MFMA. One block per 64-token chunk, 256 thr (4 waves).
// ---------------------------------------------------------------------------
__global__ __launch_bounds__(256)
void k_conf2(const float* __restrict__ o_p, const u32* __restrict__ img_c,
             const float* __restrict__ bc1, const float* __restrict__ Wc2,
             const float* __restrict__ bc2, const float* __restrict__ wts,
             const int* __restrict__ cnt, const int* __restrict__ tlist,
             const int* __restrict__ chunk2e, const int* __restrict__ chunkloc,
             float* __restrict__ cw) {
  __shared__ u32 stg[8192];   // 32 KB: full Wc1e image (16 steps x 512 u32)
  __shared__ int tke[64];
  const int c = remap_chunk(blockIdx.x);
  const int e = chunk2e[c];
  if (e < 0) return;
  const int loc = chunkloc[c];
  const int nt = cnt[e];
  const int tid = threadIdx.x;
  const int w = tid >> 6, lane = tid & 63;
  const int l15 = lane & 15, q = lane >> 4;

  const u32* src = img_c + (size_t)e * 16 * 512;
#pragma unroll
  for (int i = 0; i < 8; ++i)
    gload_lds16(src + tid * 4 + i * 1024, stg + tid * 4 + i * 1024);
  if (tid < 64) {
    int i = min(loc * 64 + tid, nt - 1);
    tke[tid] = tlist[(size_t)e * BT + i];
  }
  __syncthreads();   // stage drained + tke visible

  const int rows_c = min(64, nt - loc * 64);
  const int local = w * 16 + l15;
  const int ent = tke[local];
  const float* orow = o_p + (size_t)ent * DD;

  f32x4 acc0 = {0.f, 0.f, 0.f, 0.f}, acc1 = {0.f, 0.f, 0.f, 0.f};
#pragma unroll
  for (int st = 0; st < 16; ++st) {
    float4 f0 = *reinterpret_cast<const float4*>(orow + st * 32 + q * 8);
    float4 f1 = *reinterpret_cast<const float4*>(orow + st * 32 + q * 8 + 4);
    u32x4 bp = { pack2bf(f0.x, f0.y), pack2bf(f0.z, f0.w),
                 pack2bf(f1.x, f1.y), pack2bf(f1.z, f1.w) };
    short8 bfrag = __builtin_bit_cast(short8, bp);
    short8 af0 = *reinterpret_cast<const short8*>(
        stg + st * 512 + q * 128 + l15 * 4);
    short8 af1 = *reinterpret_cast<const short8*>(
        stg + st * 512 + q * 128 + (16 + l15) * 4);
    acc0 = __builtin_amdgcn_mfma_f32_16x16x32_bf16(af0, bfrag, acc0, 0, 0, 0);
    acc1 = __builtin_amdgcn_mfma_f32_16x16x32_bf16(af1, bfrag, acc1, 0, 0, 0);
  }

  float part = 0.f;
#pragma unroll
  for (int i = 0; i < 4; ++i) {
    int ch0 = q * 4 + i, ch1 = 16 + q * 4 + i;
    float h0 = fmaxf(acc0[i] + bc1[(size_t)e * CHN + ch0], 0.f);
    float h1 = fmaxf(acc1[i] + bc1[(size_t)e * CHN + ch1], 0.f);
    part = fmaf(h0, Wc2[(size_t)e * CHN + ch0], part);
    part = fmaf(h1, Wc2[(size_t)e * CHN + ch1], part);
  }
  part += __shfl_xor(part, 16);
  part += __shfl_xor(part, 32);
  if (q == 0 && local < rows_c) {
    float cv = 1.f / (1.f + expf(-(part + bc2[e])));
    cw[ent] = wts[(size_t)(ent >> 2) * EE + e] * cv;
  }
}

// ---------------------------------------------------------------------------
// Combine: out[t] = sum_s cw*o / (sum_s cw + eps)
// ---------------------------------------------------------------------------
__global__ __launch_bounds__(256)
void k_combine(const float* __restrict__ o_p, const float* __restrict__ cw,
               float* __restrict__ out) {
  int gid = blockIdx.x * 256 + threadIdx.x;
  int t = gid >> 7;
  int j = gid & 127;
  float c0 = cw[t * 4 + 0], c1 = cw[t * 4 + 1];
  float c2 = cw[t * 4 + 2], c3 = cw[t * 4 + 3];
  float den = c0 + c1 + c2 + c3 + 1e-6f;
  const float4* base = reinterpret_cast<const float4*>(o_p) + (size_t)t * 4 * 128;
  float4 v0 = base[0 * 128 + j];
  float4 v1 = base[1 * 128 + j];
  float4 v2 = base[2 * 128 + j];
  float4 v3 = base[3 * 128 + j];
  float4 r;
  r.x = (c0 * v0.x + c1 * v1.x + c2 * v2.x + c3 * v3.x) / den;
  r.y = (c0 * v0.y + c1 * v1.y + c2 * v2.y + c3 * v3.y) / den;
  r.z = (c0 * v0.z + c1 * v1.z + c2 * v2.z + c3 * v3.z) / den;
  r.w = (c0 * v0.w + c1 * v1.w + c2 * v2.w + c3 * v3.w) / den;
  reinterpret_cast<float4*>(out)[gid] = r;
}

extern "C" void kernel_launch(void* const* d_in, const int* in_sizes, int n_in,
                              void* d_out, int out_size, void* d_ws, size_t ws_size,
                              hipStream_t stream) {
  const float* x   = (const float*)d_in[0];
  const float* W1  = (const float*)d_in[1];
  const float* b1  = (const float*)d_in[2];
  const float* W2  = (const float*)d_in[3];
  const float* b2  = (const float*)d_in[4];
  const float* Wg1 = (const float*)d_in[5];
  const float* bg1 = (const float*)d_in[6];
  const float* Wg2 = (const float*)d_in[7];
  const float* bg2 = (const float*)d_in[8];
  const float* Wc1 = (const float*)d_in[9];
  const float* bc1 = (const float*)d_in[10];
  const float* Wc2 = (const float*)d_in[11];
  const float* bc2 = (const float*)d_in[12];
  float* out = (float*)d_out;

  // workspace layout (~64 MB)
  char* p = (char*)d_ws;
  u16* xb = (u16*)p;            p += (size_t)BT * DD * 2;            // 2 MB
  u32* img = (u32*)p;           p += (size_t)64 * 4 * 16 * 2048 * 4; // 32 MB
  float* h_g = (float*)p;                                            // gate h (4 MB)
  u32* hid = (u32*)p;           p += (size_t)MAXCH * 64 * DD * 2;    // 10 MB (aliases h_g; disjoint in time)
  float* wts = (float*)p;       p += (size_t)BT * EE * 4;            // 256 KB
  float* cw  = (float*)p;       p += (size_t)BT * KK * 4;            // 32 KB
  float* o_p = (float*)p;       p += (size_t)BT * KK * DD * 4;       // 16 MB
  int* cnt = (int*)p;           p += 256;
  int* tlist = (int*)p;         p += (size_t)EE * BT * 4;            // 256 KB
  int* chunk2e = (int*)p;       p += 1024;
  int* chunkloc = (int*)p;      p += 1024;
  u32* img_c = (u32*)p;         p += (size_t)EE * 16 * 512 * 4;      // 1 MB
  int* topi = (int*)p;          p += (size_t)BT * KK * 4;            // 32 KB

  k_prep<<<NB_PREP, 256, 0, stream>>>(x, W1, W2, Wc1, Wg1, bg1,
                                      xb, img, img_c, h_g);
  k_gate_route<<<BT / 8, 256, 0, stream>>>(h_g, Wg2, bg2, wts, topi);
  k_build<<<1, 1024, 0, stream>>>(topi, cnt, tlist, chunk2e, chunkloc);
  k_gemm1<<<dim3(MAXCH, 4), 256, 0, stream>>>(xb, img, b1, cnt, tlist,
                                              chunk2e, chunkloc, hid);
  k_gemm2<<<dim3(MAXCH, 4), 256, 0, stream>>>(hid, img, b2, cnt, tlist,
                                              chunk2e, chunkloc, o_p);
  k_conf2<<<MAXCH, 256, 0, stream>>>(o_p, img_c, bc1, Wc2, bc2, wts,
                                     cnt, tlist, chunk2e, chunkloc, cw);
  k_combine<<<(BT * (DD / 4)) / 256, 256, 0, stream>>>(o_p, cw, out);
}